// Round 7
// baseline (383.782 us; speedup 1.0000x reference)
//
#include <hip/hip_runtime.h>

// Problem constants (fixed by setup_inputs): x (4, 64, 8192, 1) fp32, k=9, dilation=1
#define BB 4
#define DD 64
#define NN 8192
#define KK 9

// ---------------------------------------------------------------------------
// MFMA filter + exact rescan
//   K1 knorm2: normalize, emit fp32 xnT, sq, fp16 casts P=fp16(xn), S=fp16(-2xn)
//   K2 kmin:   pure-fp16 MFMA GEMM -> per-(row, 16-j-group) min of approx -2*dot
//              (minbuf units = "-2*dot", no sq_j term), LDS-staged full-line
//              stores: minbuf[row*512+g], g = half*256 + tile.
//              R7: jsplits 4->8 (2048 blocks, 32 waves/CU) — R2 PMC showed
//              MfmaUtil 16/VALU 6 => latency-bound; double wave overlap.
//   K3 ksel:   HALF-WAVE per row (R7): lanes 0-31 = row A, 32-63 = row B.
//              R6 post-mortem: per-wave VALU ~2.1K with VALUBusy 31% at 42%
//              occupancy — fixed serial chains (HBM minbuf load, shfl bitonics,
//              ballot chains) dominate; halving WAVE COUNT halves per-row cost
//              of every phase. All cross-lane ops stay within a half
//              (xor-distance <= 16); ballots use the half's 32-bit slice.
//     th9p  = 9th-smallest of the half's 32 lane-mins (15-stage bitonic)
//             [9 smallest lane-mins = 9 DISTINCT groups each with approx-min
//              <= th9p => same kappa2/theta proofs as R6, window only widens]
//     theta = th9p + 8e-3 group window; kappa2 = th9p + 4e-3 cutoff on -2*dot
//             (err <= 2.5e-3 rigorous fp16 bound, R6-verified)
//     top-9 = 15-stage u64 bitonic of <=32 survivors per half; l31==r -> rank r
//     Fallbacks: cnt>40 groups -> exact full scan; S>32 -> per-lane kd[9].
// Fallback to the original verified path if ws_size is too small.
// ---------------------------------------------------------------------------

typedef __attribute__((ext_vector_type(8))) _Float16 f16x8;  // 4 VGPR MFMA operand
typedef __attribute__((ext_vector_type(16))) float f32x16;   // 32x32 accumulator

__device__ __forceinline__ uint4 pack8(const unsigned* w) {
    return make_uint4(w[0] | (w[1] << 16), w[2] | (w[3] << 16),
                      w[4] | (w[5] << 16), w[6] | (w[7] << 16));
}

__device__ __forceinline__ float min3f(float a, float b, float c) {
    return fminf(fminf(a, b), c);            // clang fuses to v_min3_f32
}

// ---------------- K1: normalize + fp32 pack + sq + fp16 casts -----------------
__global__ __launch_bounds__(256) void knorm2_kernel(const float* __restrict__ x,
                                                     float* __restrict__ xnT,
                                                     float* __restrict__ sq,
                                                     unsigned short* __restrict__ Phi,
                                                     unsigned short* __restrict__ Shi) {
    int t = blockIdx.x * 256 + threadIdx.x;      // row id 0..B*N-1
    int b = t >> 13;
    int n = t & (NN - 1);
    const float* xb = x + (size_t)b * DD * NN + n;
    float v[DD];
    float ss = 0.0f;
#pragma unroll
    for (int d = 0; d < DD; ++d) {
        v[d] = xb[(size_t)d * NN];
        ss = fmaf(v[d], v[d], ss);
    }
    float inv = 1.0f / fmaxf(sqrtf(ss), 1e-12f);
    float s2 = 0.0f;
#pragma unroll
    for (int d = 0; d < DD; ++d) {
        v[d] *= inv;
        s2 = fmaf(v[d], v[d], s2);
    }
    sq[t] = s2;
    float4* o4 = reinterpret_cast<float4*>(xnT + (size_t)t * DD);
#pragma unroll
    for (int d = 0; d < DD; d += 4) o4[d >> 2] = make_float4(v[d], v[d+1], v[d+2], v[d+3]);

    size_t base = (size_t)t * DD;
#pragma unroll
    for (int d0 = 0; d0 < DD; d0 += 8) {
        unsigned ph[8], sh[8];
#pragma unroll
        for (int e = 0; e < 8; ++e) {
            float f = v[d0 + e];
            _Float16 hp = (_Float16)f;               // v_cvt_f16_f32 (RNE)
            _Float16 hs = (_Float16)(-2.0f * f);     // exact scale before rounding
            ph[e] = (unsigned)__builtin_bit_cast(unsigned short, hp);
            sh[e] = (unsigned)__builtin_bit_cast(unsigned short, hs);
        }
        *reinterpret_cast<uint4*>(Phi + base + d0) = pack8(ph);
        *reinterpret_cast<uint4*>(Shi + base + d0) = pack8(sh);
    }
}

// ---------------- K2: MFMA min pass (fp16, LDS-staged writes, 8 jsplits) -----
// Wave = 32 i-rows; block = 4 waves = 128 rows; grid (256 rowblocks, 8 jsplits).
// Per tile, lane (l31,half) -> min of its 16 C-values = group g = half*256 +
// (goff+tt) for row i0+l31. Mins staged in wave-private LDS [32][33], flushed
// every 16 tiles as wave-wide float4 full-line stores (R2 post-mortem).
__global__ __launch_bounds__(256, 4) void kmin_kernel(const unsigned short* __restrict__ Shi,
                                                      const unsigned short* __restrict__ Phi,
                                                      float* __restrict__ minbuf) {
    __shared__ float stage[4][32][33];                  // 16.9 KB/block
    const int lane = threadIdx.x & 63;
    const int wave = threadIdx.x >> 6;
    const int l31 = lane & 31;
    const int half = lane >> 5;
    const int i0 = blockIdx.x * 128 + wave * 32;        // global i-row base
    const int b = i0 >> 13;
    const int jloc0 = blockIdx.y * (NN / 8);            // batch-local j start
    const int goff = jloc0 >> 5;                        // tile base (32 per split)
    const int row = i0 + l31;

    f16x8 Bh[4];
    {
        const size_t ib = (size_t)row * DD + half * 8;
#pragma unroll
        for (int kc = 0; kc < 4; ++kc)
            Bh[kc] = *reinterpret_cast<const f16x8*>(Phi + ib + kc * 16);
    }
    const size_t ja0 = ((size_t)b * NN + jloc0 + l31) * DD + half * 8;

#pragma unroll 1
    for (int f = 0; f < 2; ++f) {
#pragma unroll 4
        for (int u = 0; u < 16; ++u) {
            const int tt = f * 16 + u;
            const size_t ja = ja0 + (size_t)tt * 32 * DD;
            f16x8 Ah[4];
#pragma unroll
            for (int kc = 0; kc < 4; ++kc)
                Ah[kc] = *reinterpret_cast<const f16x8*>(Shi + ja + kc * 16);
            f32x16 c = {};
#pragma unroll
            for (int kc = 0; kc < 4; ++kc)
                c = __builtin_amdgcn_mfma_f32_32x32x16_f16(Ah[kc], Bh[kc], c, 0, 0, 0);
            float t0 = min3f(c[0], c[1], c[2]);
            float t1 = min3f(c[3], c[4], c[5]);
            float t2 = min3f(c[6], c[7], c[8]);
            float t3 = min3f(c[9], c[10], c[11]);
            float t4 = min3f(c[12], c[13], c[14]);
            stage[wave][l31][half * 16 + u] =
                fminf(min3f(t0, t1, t2), min3f(t3, t4, c[15]));
        }
        // flush: wave-private LDS -> full-line global stores (no barrier needed)
        const int gbase = goff + f * 16;
#pragma unroll
        for (int it = 0; it < 4; ++it) {
            int idx = it * 64 + lane;
            int c4 = idx & 3;
            int hf = (idx >> 2) & 1;
            int r = idx >> 3;                            // 0..31
            const float* s = &stage[wave][r][hf * 16 + c4 * 4];
            float4 vv = make_float4(s[0], s[1], s[2], s[3]);
            *reinterpret_cast<float4*>(minbuf + (size_t)(i0 + r) * 512 +
                                       hf * 256 + gbase + c4 * 4) = vv;
        }
    }
}

// ---------------- K3: half-wave per row ksel ---------------------------------
__global__ __launch_bounds__(256) void ksel_kernel(const float* __restrict__ xnT,
                                                   const float* __restrict__ sq,
                                                   const float* __restrict__ minbuf,
                                                   int* __restrict__ out) {
    __shared__ unsigned short glist[4][2][40];
    __shared__ unsigned long long surv[4][2][32];
    const int lane = threadIdx.x & 63;
    const int wave = threadIdx.x >> 6;
    const int l31 = lane & 31;
    const int half = lane >> 5;
    const int t = blockIdx.x * 8 + wave * 2 + half;      // this half's row
    const int b = t >> 13;                               // block-uniform (8 | 8192)
    const int n = t & (NN - 1);

    // lane's 16 group-mins (rows A+B: 4KB coalesced per wave)
    float gm[16];
    {
        const float4* m4 = reinterpret_cast<const float4*>(minbuf + (size_t)t * 512 + l31 * 16);
#pragma unroll
        for (int q4 = 0; q4 < 4; ++q4) {
            float4 a = m4[q4];
            gm[q4 * 4 + 0] = a.x; gm[q4 * 4 + 1] = a.y;
            gm[q4 * 4 + 2] = a.z; gm[q4 * 4 + 3] = a.w;
        }
    }

    // th9p: 15-stage bitonic of the half's 32 lane-mins; l31==8 holds 9th-smallest
    float sv;
    {
        float t0 = min3f(gm[0], gm[1], gm[2]);
        float t1 = min3f(gm[3], gm[4], gm[5]);
        float t2 = min3f(gm[6], gm[7], gm[8]);
        float t3 = min3f(gm[9], gm[10], gm[11]);
        float t4 = min3f(gm[12], gm[13], gm[14]);
        sv = fminf(min3f(t0, t1, t2), min3f(t3, t4, gm[15]));
    }
#pragma unroll
    for (int k = 2; k <= 32; k <<= 1) {
#pragma unroll
        for (int jj = k >> 1; jj >= 1; jj >>= 1) {       // jj<=16: stays in half
            float o = __shfl_xor(sv, jj);
            bool keepMin = (((l31 & jj) == 0) == ((l31 & k) == 0));
            sv = keepMin ? fminf(sv, o) : fmaxf(sv, o);
        }
    }
    const float th9p = __shfl(sv, (lane & 32) + 8);      // broadcast within half
    const float theta = th9p + 8e-3f;     // group window (minbuf units)
    const float kappa2F = th9p + 4e-3f;   // survivor cutoff on -2*dot

    // half-ballot compaction of candidate groups (lane owns groups l31*16+q)
    int cnt = 0;
    unsigned short* gl = &glist[wave][half][0];
#pragma unroll
    for (int q = 0; q < 16; ++q) {
        bool c = gm[q] <= theta;
        unsigned long long m64 = __ballot(c);
        unsigned m32 = (unsigned)(m64 >> (half << 5));
        int pos = cnt + __popc(m32 & ((1u << l31) - 1u));
        if (c && pos < 40) gl[pos] = (unsigned short)(l31 * 16 + q);
        cnt += (int)__popc(m32);
    }
    __syncthreads();

    // row vector in VGPRs (rows differ per half -> no readfirstlane)
    const float* __restrict__ Bb = xnT + (size_t)b * NN * DD;
    const float* __restrict__ sqb = sq + (size_t)b * NN;
    float ar[DD];
    {
        const float4* a4 = reinterpret_cast<const float4*>(xnT + (size_t)t * DD);
#pragma unroll
        for (int d = 0; d < DD; d += 4) {
            float4 f = a4[d >> 2];
            ar[d] = f.x; ar[d + 1] = f.y; ar[d + 2] = f.z; ar[d + 3] = f.w;
        }
    }

    // exact fp32 rescan over the half's candidates; survivors compact to LDS
    const bool ovf = (cnt > 40);
    const int total = ovf ? NN : cnt * 16;
    const int nIt = (total + 31) >> 5;
    int S = 0;
#pragma unroll 1
    for (int m = 0; m < nIt; ++m) {
        const int idx = m * 32 + l31;
        const bool act = idx < total;
        unsigned long long cnd = ~0ULL;
        float m2dot = __uint_as_float(0x7f800000u);      // +inf for inactive
        if (act) {
            int j;
            if (ovf) {
                j = idx;
            } else {
                int g = (int)gl[idx >> 4];
                int s4 = idx & 15;
                j = (g & 255) * 32 + ((s4 >> 2) * 8) + ((g >> 8) * 4) + (s4 & 3);
            }
            const float4* bc4 = reinterpret_cast<const float4*>(Bb + (size_t)j * DD);
            float a0 = 0.0f, a1 = 0.0f, a2 = 0.0f, a3 = 0.0f;
#pragma unroll
            for (int d4 = 0; d4 < DD / 4; ++d4) {
                float4 f = bc4[d4];
                a0 = fmaf(ar[4 * d4 + 0], f.x, a0);
                a1 = fmaf(ar[4 * d4 + 1], f.y, a1);
                a2 = fmaf(ar[4 * d4 + 2], f.z, a2);
                a3 = fmaf(ar[4 * d4 + 3], f.w, a3);
            }
            float dot = (a0 + a1) + (a2 + a3);
            m2dot = -2.0f * dot;                         // exact in fp32
            float key = fmaf(-2.0f, dot, sqb[j]);        // byte-identical ordering key
            unsigned ub = __float_as_uint(key);
            ub ^= (0x80000000u | (unsigned)((int)ub >> 31));
            cnd = ((unsigned long long)ub << 32) | (unsigned)j;
        }
        bool pass = act && (m2dot <= kappa2F);
        unsigned long long p64 = __ballot(pass);
        unsigned p32 = (unsigned)(p64 >> (half << 5));
        int pos = S + __popc(p32 & ((1u << l31) - 1u));
        if (pass && pos < 32) surv[wave][half][pos] = cnd;
        S += (int)__popc(p32);
    }
    __syncthreads();

    unsigned long long kout = ~0ULL;
    if (S <= 32) {
        // 15-stage u64 bitonic of the half's survivors; l31==r holds rank r
        unsigned long long v = (l31 < S) ? surv[wave][half][l31] : ~0ULL;
#pragma unroll
        for (int k = 2; k <= 32; k <<= 1) {
#pragma unroll
            for (int jj = k >> 1; jj >= 1; jj >>= 1) {
                unsigned long long o = __shfl_xor(v, jj);
                bool keepMin = (((l31 & jj) == 0) == ((l31 & k) == 0));
                bool less = o < v;
                unsigned long long mn = less ? o : v;
                unsigned long long mx = less ? v : o;
                v = keepMin ? mn : mx;
            }
        }
        kout = v;
    } else {
        // rare: per-lane kd[9] + 9-round half-butterfly (keys unique: j in bits)
        unsigned long long kd[KK];
#pragma unroll
        for (int m = 0; m < KK; ++m) kd[m] = ~0ULL;
#pragma unroll 1
        for (int m = 0; m < nIt; ++m) {
            const int idx = m * 32 + l31;
            if (idx >= total) continue;
            int j;
            if (ovf) {
                j = idx;
            } else {
                int g = (int)gl[idx >> 4];
                int s4 = idx & 15;
                j = (g & 255) * 32 + ((s4 >> 2) * 8) + ((g >> 8) * 4) + (s4 & 3);
            }
            const float4* bc4 = reinterpret_cast<const float4*>(Bb + (size_t)j * DD);
            float a0 = 0.0f, a1 = 0.0f, a2 = 0.0f, a3 = 0.0f;
#pragma unroll
            for (int d4 = 0; d4 < DD / 4; ++d4) {
                float4 f = bc4[d4];
                a0 = fmaf(ar[4 * d4 + 0], f.x, a0);
                a1 = fmaf(ar[4 * d4 + 1], f.y, a1);
                a2 = fmaf(ar[4 * d4 + 2], f.z, a2);
                a3 = fmaf(ar[4 * d4 + 3], f.w, a3);
            }
            float dot = (a0 + a1) + (a2 + a3);
            float key = fmaf(-2.0f, dot, sqb[j]);
            unsigned ub = __float_as_uint(key);
            ub ^= (0x80000000u | (unsigned)((int)ub >> 31));
            unsigned long long cnd = ((unsigned long long)ub << 32) | (unsigned)j;
            if (cnd < kd[KK - 1]) {
#pragma unroll
                for (int m2 = 0; m2 < KK; ++m2) {
                    bool sw = cnd < kd[m2];
                    unsigned long long lo = sw ? cnd : kd[m2];
                    unsigned long long hi = sw ? kd[m2] : cnd;
                    kd[m2] = lo;
                    cnd = hi;
                }
            }
        }
#pragma unroll
        for (int r = 0; r < KK; ++r) {
            unsigned long long c = kd[0];
            unsigned long long wm = c;
#pragma unroll
            for (int d = 1; d < 32; d <<= 1) {           // half-butterfly
                unsigned long long o = __shfl_xor(wm, d);
                wm = (o < wm) ? o : wm;
            }
            if (l31 == r) kout = wm;
            if (c == wm) {
#pragma unroll
                for (int m2 = 0; m2 < KK - 1; ++m2) kd[m2] = kd[m2 + 1];
                kd[KK - 1] = ~0ULL;
            }
        }
    }

    if (l31 < KK) {
        out[(size_t)t * KK + l31] = (int)(kout & 0xFFFFFFFFULL);
        out[(size_t)BB * NN * KK + (size_t)t * KK + l31] = n;
    }
}

// ===========================================================================
// OLD PATH (verified fallback) -- unchanged
// ===========================================================================
__global__ __launch_bounds__(256) void knorm_kernel(const float* __restrict__ x,
                                                    float* __restrict__ xnT,
                                                    float* __restrict__ sq) {
    int t = blockIdx.x * 256 + threadIdx.x;
    int b = t >> 13;
    int n = t & (NN - 1);
    const float* xb = x + (size_t)b * DD * NN + n;
    float v[DD];
    float ss = 0.0f;
#pragma unroll
    for (int d = 0; d < DD; ++d) {
        v[d] = xb[(size_t)d * NN];
        ss = fmaf(v[d], v[d], ss);
    }
    float norm = sqrtf(ss);
    float inv = 1.0f / fmaxf(norm, 1e-12f);
    float s2 = 0.0f;
#pragma unroll
    for (int d = 0; d < DD; ++d) {
        float xv = v[d] * inv;
        v[d] = xv;
        s2 = fmaf(xv, xv, s2);
    }
    float4* o4 = reinterpret_cast<float4*>(xnT + (size_t)t * DD);
#pragma unroll
    for (int d = 0; d < DD; d += 4) {
        o4[d >> 2] = make_float4(v[d], v[d + 1], v[d + 2], v[d + 3]);
    }
    sq[t] = s2;
}

template <int S>
__global__ __launch_bounds__(256, 2) void kdist_kernel(const float* __restrict__ xnT,
                                                       const float* __restrict__ sq,
                                                       unsigned long long* __restrict__ cand) {
    const int rb = blockIdx.x;
    const int b = rb >> 5;
    const int nbase = (rb & 31) * 256;
    const int n = nbase + threadIdx.x;
    const int s = blockIdx.y;
    const int jcount = NN / S;
    const int j0 = s * jcount;
    const int j1 = j0 + jcount;

    const float* __restrict__ Bb = xnT + ((size_t)b * NN) * DD;
    const float* __restrict__ sqb = sq + (size_t)b * NN;

    float ar[DD];
    {
        const float4* a4 = reinterpret_cast<const float4*>(Bb + (size_t)n * DD);
#pragma unroll
        for (int d = 0; d < DD; d += 4) {
            float4 f = a4[d >> 2];
            ar[d] = f.x; ar[d + 1] = f.y; ar[d + 2] = f.z; ar[d + 3] = f.w;
        }
    }
#pragma unroll
    for (int d = 0; d < DD; ++d) {
        asm volatile("" : "+v"(ar[d]));
    }

    unsigned long long kd[KK];
#pragma unroll
    for (int m = 0; m < KK; ++m) kd[m] = ~0ULL;

#pragma unroll 2
    for (int j = j0; j < j1; ++j) {
        const float4* bc4 = reinterpret_cast<const float4*>(Bb + (size_t)j * DD);
        float a0 = 0.0f, a1 = 0.0f, a2 = 0.0f, a3 = 0.0f;
#pragma unroll
        for (int d4 = 0; d4 < DD / 4; ++d4) {
            float4 f = bc4[d4];
            a0 = fmaf(ar[4 * d4 + 0], f.x, a0);
            a1 = fmaf(ar[4 * d4 + 1], f.y, a1);
            a2 = fmaf(ar[4 * d4 + 2], f.z, a2);
            a3 = fmaf(ar[4 * d4 + 3], f.w, a3);
        }
        float dot = (a0 + a1) + (a2 + a3);
        float key = fmaf(-2.0f, dot, sqb[j]);
        unsigned int ub = __float_as_uint(key);
        ub ^= (0x80000000u | (unsigned int)((int)ub >> 31));
        unsigned long long cnd = ((unsigned long long)ub << 32) | (unsigned int)j;
        if (cnd < kd[KK - 1]) {
#pragma unroll
            for (int m = 0; m < KK; ++m) {
                bool sw = cnd < kd[m];
                unsigned long long lo = sw ? cnd : kd[m];
                unsigned long long hi = sw ? kd[m] : cnd;
                kd[m] = lo;
                cnd = hi;
            }
        }
    }

    unsigned long long* outc = cand + ((size_t)(b * NN + n) * S + s) * KK;
#pragma unroll
    for (int m = 0; m < KK; ++m) outc[m] = kd[m];
}

template <int S>
__global__ __launch_bounds__(256) void kmerge_kernel(const unsigned long long* __restrict__ cand,
                                                     int* __restrict__ out) {
    int t = blockIdx.x * 256 + threadIdx.x;
    const unsigned long long* c = cand + (size_t)t * (S * KK);
    unsigned long long kd[KK];
#pragma unroll
    for (int m = 0; m < KK; ++m) kd[m] = ~0ULL;
#pragma unroll
    for (int q = 0; q < S * KK; ++q) {
        unsigned long long cnd = c[q];
        if (cnd < kd[KK - 1]) {
#pragma unroll
            for (int m = 0; m < KK; ++m) {
                bool sw = cnd < kd[m];
                unsigned long long lo = sw ? cnd : kd[m];
                unsigned long long hi = sw ? kd[m] : cnd;
                kd[m] = lo;
                cnd = hi;
            }
        }
    }
    int n = t & (NN - 1);
    int* out0 = out + (size_t)t * KK;
    int* out1 = out + (size_t)BB * NN * KK + (size_t)t * KK;
#pragma unroll
    for (int m = 0; m < KK; ++m) {
        out0[m] = (int)(kd[m] & 0xFFFFFFFFULL);
        out1[m] = n;
    }
}

extern "C" void kernel_launch(void* const* d_in, const int* in_sizes, int n_in,
                              void* d_out, int out_size, void* d_ws, size_t ws_size,
                              hipStream_t stream) {
    const float* x = (const float*)d_in[0];
    int* out = (int*)d_out;
    char* ws = (char*)d_ws;

    // Shared layout head
    constexpr size_t XNT_B = (size_t)BB * NN * DD * 4;          //  8,388,608
    constexpr size_t SQ_B  = (size_t)BB * NN * 4;               //    131,072
    float* xnT = (float*)ws;
    float* sq  = (float*)(ws + XNT_B);

    // New-path layout (offsets kept from the verified R2 layout; Plo/Slo slots
    // are unused but reserved so NEED_NEW is unchanged)
    constexpr size_t BF_B  = (size_t)BB * NN * DD * 2;          //  4,194,304 each
    constexpr size_t OFF_PHI = XNT_B + SQ_B;
    constexpr size_t OFF_PLO = OFF_PHI + BF_B;
    constexpr size_t OFF_SHI = OFF_PLO + BF_B;
    constexpr size_t OFF_SLO = OFF_SHI + BF_B;
    constexpr size_t OFF_MIN = OFF_SLO + BF_B;
    constexpr size_t MIN_B   = (size_t)512 * BB * NN * 4;       // 67,108,864
    constexpr size_t NEED_NEW = OFF_MIN + MIN_B;                // 92,405,760

    if (ws_size >= NEED_NEW) {
        unsigned short* Phi = (unsigned short*)(ws + OFF_PHI);
        unsigned short* Shi = (unsigned short*)(ws + OFF_SHI);
        float* minbuf = (float*)(ws + OFF_MIN);

        knorm2_kernel<<<dim3(BB * NN / 256), dim3(256), 0, stream>>>(x, xnT, sq, Phi, Shi);
        kmin_kernel<<<dim3(BB * NN / 128, 8), dim3(256), 0, stream>>>(Shi, Phi, minbuf);
        ksel_kernel<<<dim3(BB * NN / 8), dim3(256), 0, stream>>>(xnT, sq, minbuf, out);
        return;
    }

    // Old verified path
    unsigned long long* cand = (unsigned long long*)(ws + XNT_B + SQ_B);
    const size_t base = XNT_B + SQ_B;
    const size_t need8 = base + (size_t)BB * NN * 8 * KK * 8;

    knorm_kernel<<<dim3(BB * NN / 256), dim3(256), 0, stream>>>(x, xnT, sq);
    if (ws_size >= need8) {
        kdist_kernel<8><<<dim3(BB * NN / 256, 8), dim3(256), 0, stream>>>(xnT, sq, cand);
        kmerge_kernel<8><<<dim3(BB * NN / 256), dim3(256), 0, stream>>>(cand, out);
    } else {
        kdist_kernel<4><<<dim3(BB * NN / 256, 4), dim3(256), 0, stream>>>(xnT, sq, cand);
        kmerge_kernel<4><<<dim3(BB * NN / 256), dim3(256), 0, stream>>>(cand, out);
    }
}

// Round 8
// 249.270 us; speedup vs baseline: 1.5396x; 1.5396x over previous
//
#include <hip/hip_runtime.h>

// Problem constants (fixed by setup_inputs): x (4, 64, 8192, 1) fp32, k=9, dilation=1
#define BB 4
#define DD 64
#define NN 8192
#define KK 9

// ---------------------------------------------------------------------------
// MFMA filter + exact rescan
//   K1 knorm2: normalize, emit fp32 xnT, sq, fp16 casts P=fp16(xn), S=fp16(-2xn)
//   K2 kmin:   fp16 MFMA GEMM -> per-(row, 16-j-group) min of approx -2*dot
//              (minbuf units = "-2*dot"). R8: 64 i-rows/wave (two B-fragment
//              sets share each A-tile load: 8 MFMA per 4 loads — R7 showed
//              kmin is A-load-bound, not occupancy-bound). LDS-staged
//              full-line stores: minbuf[row*512+g], g = half*256 + tile.
//   K3 ksel:   wave-per-row (R6-proven base: readfirstlane row => scalar ar,
//              52 VGPR, 42% occ; R7's half-wave variant REGRESSED via VGPR).
//              R8: TWO-STAGE rescan:
//       th9p  = 9th-smallest lane-min (21-stage f32 bitonic)  [R6-proven]
//       theta = th9p + 8e-3 group window                       [R6-proven]
//       stage1: gather fp16 Phi rows (128B, 4MB = L2-resident; was 256B fp32
//               from 8MB) , dot vs EXACT fp32 ar; keep j if
//               -2*ap <= kappa1 = th9p + 5.5e-3.
//               |ap-dot| <= 2^-11*||x_j||*||x_i|| + accum ~= 5e-4 => m2 err
//               <= ~1.0e-3. Top-9 j: m2dot <= th9p+2.5e-3+dSq (R6 proof) =>
//               m2ap <= th9p+3.6e-3 < kappa1 (margin 1.9e-3). S1>=9 by the
//               9-distinct-group witness argument.
//       stage2: exact fp32 key for the <=64 stage-1 survivors, ONE 21-stage
//               u64 bitonic. No kappa2 filter needed: top-9 subset of stage-1
//               => sorting stage-1's exact keys reproduces reference output
//               (incl. tie-break; keys unique via j in low bits).
//       Fallbacks: cnt>40 groups -> full scan; S1>64 -> exact per-lane kd[9].
// Fallback to the original verified path if ws_size is too small.
// ---------------------------------------------------------------------------

typedef __attribute__((ext_vector_type(8))) _Float16 f16x8;  // 4 VGPR MFMA operand
typedef __attribute__((ext_vector_type(16))) float f32x16;   // 32x32 accumulator

__device__ __forceinline__ uint4 pack8(const unsigned* w) {
    return make_uint4(w[0] | (w[1] << 16), w[2] | (w[3] << 16),
                      w[4] | (w[5] << 16), w[6] | (w[7] << 16));
}

__device__ __forceinline__ float min3f(float a, float b, float c) {
    return fminf(fminf(a, b), c);            // clang fuses to v_min3_f32
}

// ---------------- K1: normalize + fp32 pack + sq + fp16 casts -----------------
__global__ __launch_bounds__(256) void knorm2_kernel(const float* __restrict__ x,
                                                     float* __restrict__ xnT,
                                                     float* __restrict__ sq,
                                                     unsigned short* __restrict__ Phi,
                                                     unsigned short* __restrict__ Shi) {
    int t = blockIdx.x * 256 + threadIdx.x;      // row id 0..B*N-1
    int b = t >> 13;
    int n = t & (NN - 1);
    const float* xb = x + (size_t)b * DD * NN + n;
    float v[DD];
    float ss = 0.0f;
#pragma unroll
    for (int d = 0; d < DD; ++d) {
        v[d] = xb[(size_t)d * NN];
        ss = fmaf(v[d], v[d], ss);
    }
    float inv = 1.0f / fmaxf(sqrtf(ss), 1e-12f);
    float s2 = 0.0f;
#pragma unroll
    for (int d = 0; d < DD; ++d) {
        v[d] *= inv;
        s2 = fmaf(v[d], v[d], s2);
    }
    sq[t] = s2;
    float4* o4 = reinterpret_cast<float4*>(xnT + (size_t)t * DD);
#pragma unroll
    for (int d = 0; d < DD; d += 4) o4[d >> 2] = make_float4(v[d], v[d+1], v[d+2], v[d+3]);

    size_t base = (size_t)t * DD;
#pragma unroll
    for (int d0 = 0; d0 < DD; d0 += 8) {
        unsigned ph[8], sh[8];
#pragma unroll
        for (int e = 0; e < 8; ++e) {
            float f = v[d0 + e];
            _Float16 hp = (_Float16)f;               // v_cvt_f16_f32 (RNE)
            _Float16 hs = (_Float16)(-2.0f * f);     // exact scale before rounding
            ph[e] = (unsigned)__builtin_bit_cast(unsigned short, hp);
            sh[e] = (unsigned)__builtin_bit_cast(unsigned short, hs);
        }
        *reinterpret_cast<uint4*>(Phi + base + d0) = pack8(ph);
        *reinterpret_cast<uint4*>(Shi + base + d0) = pack8(sh);
    }
}

// ---------------- K2: MFMA min pass (fp16, 64 rows/wave, LDS-staged) ---------
// Wave = 64 i-rows (two 32-row B-fragment sets sharing each A tile);
// block = 4 waves = 256 rows; grid (128 rowblocks, 8 jsplits), 32 tiles/wave.
// Per tile: 4 A-loads, 8 MFMA (A-traffic per MFMA halved vs R6 — R7 showed
// kmin is A-load-bound). Mins staged in wave-private LDS [64][33] (2-way bank
// alias = free), flushed per 16-tile chunk as full-line float4 stores.
__global__ __launch_bounds__(256, 4) void kmin_kernel(const unsigned short* __restrict__ Shi,
                                                      const unsigned short* __restrict__ Phi,
                                                      float* __restrict__ minbuf) {
    __shared__ float stage[4][64][33];                  // 33.8 KB/block
    const int lane = threadIdx.x & 63;
    const int wave = threadIdx.x >> 6;
    const int l31 = lane & 31;
    const int half = lane >> 5;
    const int i0 = blockIdx.x * 256 + wave * 64;        // global i-row base
    const int b = i0 >> 13;                             // 256 | 8192 -> uniform
    const int jloc0 = blockIdx.y * (NN / 8);            // batch-local j start
    const int goff = jloc0 >> 5;                        // tile base (32 per split)

    f16x8 Bh0[4], Bh1[4];
    {
        const size_t ib0 = (size_t)(i0 + l31) * DD + half * 8;
        const size_t ib1 = (size_t)(i0 + 32 + l31) * DD + half * 8;
#pragma unroll
        for (int kc = 0; kc < 4; ++kc) {
            Bh0[kc] = *reinterpret_cast<const f16x8*>(Phi + ib0 + kc * 16);
            Bh1[kc] = *reinterpret_cast<const f16x8*>(Phi + ib1 + kc * 16);
        }
    }
    const size_t ja0 = ((size_t)b * NN + jloc0 + l31) * DD + half * 8;

#pragma unroll 1
    for (int f = 0; f < 2; ++f) {
#pragma unroll 2
        for (int u = 0; u < 16; ++u) {
            const int tt = f * 16 + u;
            const size_t ja = ja0 + (size_t)tt * 32 * DD;
            f16x8 Ah[4];
#pragma unroll
            for (int kc = 0; kc < 4; ++kc)
                Ah[kc] = *reinterpret_cast<const f16x8*>(Shi + ja + kc * 16);
            f32x16 c0 = {}, c1 = {};
#pragma unroll
            for (int kc = 0; kc < 4; ++kc)
                c0 = __builtin_amdgcn_mfma_f32_32x32x16_f16(Ah[kc], Bh0[kc], c0, 0, 0, 0);
#pragma unroll
            for (int kc = 0; kc < 4; ++kc)
                c1 = __builtin_amdgcn_mfma_f32_32x32x16_f16(Ah[kc], Bh1[kc], c1, 0, 0, 0);
            {
                float t0 = min3f(c0[0], c0[1], c0[2]);
                float t1 = min3f(c0[3], c0[4], c0[5]);
                float t2 = min3f(c0[6], c0[7], c0[8]);
                float t3 = min3f(c0[9], c0[10], c0[11]);
                float t4 = min3f(c0[12], c0[13], c0[14]);
                stage[wave][l31][half * 16 + u] =
                    fminf(min3f(t0, t1, t2), min3f(t3, t4, c0[15]));
            }
            {
                float t0 = min3f(c1[0], c1[1], c1[2]);
                float t1 = min3f(c1[3], c1[4], c1[5]);
                float t2 = min3f(c1[6], c1[7], c1[8]);
                float t3 = min3f(c1[9], c1[10], c1[11]);
                float t4 = min3f(c1[12], c1[13], c1[14]);
                stage[wave][32 + l31][half * 16 + u] =
                    fminf(min3f(t0, t1, t2), min3f(t3, t4, c1[15]));
            }
        }
        // flush: wave-private LDS -> full-line global stores (no barrier needed)
        const int gbase = goff + f * 16;
#pragma unroll
        for (int it = 0; it < 8; ++it) {
            int idx = it * 64 + lane;                    // 0..511
            int c4 = idx & 3;
            int hf = (idx >> 2) & 1;
            int r = idx >> 3;                            // 0..63
            const float* s = &stage[wave][r][hf * 16 + c4 * 4];
            float4 vv = make_float4(s[0], s[1], s[2], s[3]);
            *reinterpret_cast<float4*>(minbuf + (size_t)(i0 + r) * 512 +
                                       hf * 256 + gbase + c4 * 4) = vv;
        }
    }
}

// ---------------- K3: wave-per-row, bitonic theta + two-stage rescan ---------
__global__ __launch_bounds__(256) void ksel_kernel(const float* __restrict__ xnT,
                                                   const float* __restrict__ sq,
                                                   const float* __restrict__ minbuf,
                                                   const unsigned short* __restrict__ Phi,
                                                   int* __restrict__ out) {
    __shared__ unsigned short glist[4][40];
    __shared__ unsigned short jlist[4][64];
    const int lane = threadIdx.x & 63;
    const int wave = threadIdx.x >> 6;
    const int t = blockIdx.x * 4 + wave;                 // row id
    const int tu = __builtin_amdgcn_readfirstlane(t);    // wave-uniform row
    const int b = tu >> 13;
    const int n = tu & (NN - 1);

    // lane's 8 group-mins (coalesced: 2KB contiguous per wave)
    float gm[8];
    {
        const float4* m4 = reinterpret_cast<const float4*>(minbuf + (size_t)tu * 512 + lane * 8);
        float4 a = m4[0], c = m4[1];
        gm[0] = a.x; gm[1] = a.y; gm[2] = a.z; gm[3] = a.w;
        gm[4] = c.x; gm[5] = c.y; gm[6] = c.z; gm[7] = c.w;
    }

    // th9p: bitonic-sort the 64 lane-mins (ascending); lane 8 holds 9th-smallest
    float sv = fminf(min3f(gm[0], gm[1], gm[2]),
                     fminf(min3f(gm[3], gm[4], gm[5]), fminf(gm[6], gm[7])));
#pragma unroll
    for (int k = 2; k <= 64; k <<= 1) {
#pragma unroll
        for (int jj = k >> 1; jj >= 1; jj >>= 1) {
            float o = __shfl_xor(sv, jj);
            bool keepMin = (((lane & jj) == 0) == ((lane & k) == 0));
            sv = keepMin ? fminf(sv, o) : fmaxf(sv, o);
        }
    }
    const float th9p = __shfl(sv, 8);
    const float theta  = th9p + 8e-3f;     // group window (minbuf units, R6-proven)
    const float kappa1 = th9p + 5.5e-3f;   // stage-1 cutoff on -2*ap (fp16-B dot)

    // ballot-compact candidate groups into wave-private LDS list
    int cnt = 0;
    unsigned short* gl = &glist[wave][0];
#pragma unroll
    for (int q = 0; q < 8; ++q) {
        bool c = gm[q] <= theta;
        unsigned long long mask = __ballot(c);
        int pos = cnt + __popcll(mask & ((1ULL << lane) - 1ULL));
        if (c && pos < 40) gl[pos] = (unsigned short)(lane * 8 + q);
        cnt += (int)__popcll(mask);
    }
    __syncthreads();

    // row vector (wave-uniform address -> scalar/SGPR loads; R7 lesson: keep!)
    const float* __restrict__ Bb = xnT + (size_t)b * NN * DD;
    const float* __restrict__ sqb = sq + (size_t)b * NN;
    const unsigned short* __restrict__ Pb = Phi + ((size_t)b * NN) * DD;
    float ar[DD];
    {
        const float4* a4 = reinterpret_cast<const float4*>(xnT + (size_t)tu * DD);
#pragma unroll
        for (int d = 0; d < DD; d += 4) {
            float4 f = a4[d >> 2];
            ar[d] = f.x; ar[d + 1] = f.y; ar[d + 2] = f.z; ar[d + 3] = f.w;
        }
    }

    // ---- stage 1: fp16-row gather (L2-resident) + approximate filter --------
    const bool ovf = (cnt > 40);
    const int total = ovf ? NN : cnt * 16;
    const int nIt = (total + 63) >> 6;
    int S1 = 0;
    unsigned short* jl = &jlist[wave][0];
#pragma unroll 1
    for (int m = 0; m < nIt; ++m) {
        const int idx = m * 64 + lane;
        const bool act = idx < total;
        float m2ap = __uint_as_float(0x7f800000u);
        int j = 0;
        if (act) {
            if (ovf) {
                j = idx;
            } else {
                int g = (int)gl[idx >> 4];
                int s4 = idx & 15;
                j = (g & 255) * 32 + ((s4 >> 2) * 8) + ((g >> 8) * 4) + (s4 & 3);
            }
            const f16x8* p8 = reinterpret_cast<const f16x8*>(Pb + (size_t)j * DD);
            float a0 = 0.0f, a1 = 0.0f, a2 = 0.0f, a3 = 0.0f;
#pragma unroll
            for (int c8 = 0; c8 < 8; ++c8) {
                f16x8 h = p8[c8];
                a0 = fmaf((float)h[0], ar[c8 * 8 + 0], a0);
                a1 = fmaf((float)h[1], ar[c8 * 8 + 1], a1);
                a2 = fmaf((float)h[2], ar[c8 * 8 + 2], a2);
                a3 = fmaf((float)h[3], ar[c8 * 8 + 3], a3);
                a0 = fmaf((float)h[4], ar[c8 * 8 + 4], a0);
                a1 = fmaf((float)h[5], ar[c8 * 8 + 5], a1);
                a2 = fmaf((float)h[6], ar[c8 * 8 + 6], a2);
                a3 = fmaf((float)h[7], ar[c8 * 8 + 7], a3);
            }
            m2ap = -2.0f * ((a0 + a1) + (a2 + a3));
        }
        bool pass = act && (m2ap <= kappa1);
        unsigned long long mask = __ballot(pass);
        int pos = S1 + __popcll(mask & ((1ULL << lane) - 1ULL));
        if (pass && pos < 64) jl[pos] = (unsigned short)j;
        S1 += (int)__popcll(mask);
    }
    __syncthreads();

    unsigned long long kout = ~0ULL;
    if (S1 <= 64) {
        // ---- stage 2: exact fp32 keys for survivors + ONE u64 bitonic -------
        unsigned long long v = ~0ULL;
        if (lane < S1) {
            int j = (int)jl[lane];
            const float4* bc4 = reinterpret_cast<const float4*>(Bb + (size_t)j * DD);
            float a0 = 0.0f, a1 = 0.0f, a2 = 0.0f, a3 = 0.0f;
#pragma unroll
            for (int d4 = 0; d4 < DD / 4; ++d4) {
                float4 f = bc4[d4];
                a0 = fmaf(ar[4 * d4 + 0], f.x, a0);
                a1 = fmaf(ar[4 * d4 + 1], f.y, a1);
                a2 = fmaf(ar[4 * d4 + 2], f.z, a2);
                a3 = fmaf(ar[4 * d4 + 3], f.w, a3);
            }
            float dot = (a0 + a1) + (a2 + a3);
            float key = fmaf(-2.0f, dot, sqb[j]);        // byte-identical ordering key
            unsigned ub = __float_as_uint(key);
            ub ^= (0x80000000u | (unsigned)((int)ub >> 31));
            v = ((unsigned long long)ub << 32) | (unsigned)j;
        }
#pragma unroll
        for (int k = 2; k <= 64; k <<= 1) {
#pragma unroll
            for (int jj = k >> 1; jj >= 1; jj >>= 1) {
                unsigned long long o = __shfl_xor(v, jj);
                bool keepMin = (((lane & jj) == 0) == ((lane & k) == 0));
                bool less = o < v;
                unsigned long long mn = less ? o : v;
                unsigned long long mx = less ? v : o;
                v = keepMin ? mn : mx;
            }
        }
        kout = v;
    } else {
        // rare: exact per-lane kd[9] + 9-round butterfly over the candidate set
        unsigned long long kd[KK];
#pragma unroll
        for (int m = 0; m < KK; ++m) kd[m] = ~0ULL;
#pragma unroll 1
        for (int m = 0; m < nIt; ++m) {
            const int idx = m * 64 + lane;
            if (idx >= total) continue;
            int j;
            if (ovf) {
                j = idx;
            } else {
                int g = (int)gl[idx >> 4];
                int s4 = idx & 15;
                j = (g & 255) * 32 + ((s4 >> 2) * 8) + ((g >> 8) * 4) + (s4 & 3);
            }
            const float4* bc4 = reinterpret_cast<const float4*>(Bb + (size_t)j * DD);
            float a0 = 0.0f, a1 = 0.0f, a2 = 0.0f, a3 = 0.0f;
#pragma unroll
            for (int d4 = 0; d4 < DD / 4; ++d4) {
                float4 f = bc4[d4];
                a0 = fmaf(ar[4 * d4 + 0], f.x, a0);
                a1 = fmaf(ar[4 * d4 + 1], f.y, a1);
                a2 = fmaf(ar[4 * d4 + 2], f.z, a2);
                a3 = fmaf(ar[4 * d4 + 3], f.w, a3);
            }
            float dot = (a0 + a1) + (a2 + a3);
            float key = fmaf(-2.0f, dot, sqb[j]);
            unsigned ub = __float_as_uint(key);
            ub ^= (0x80000000u | (unsigned)((int)ub >> 31));
            unsigned long long cnd = ((unsigned long long)ub << 32) | (unsigned)j;
            if (cnd < kd[KK - 1]) {
#pragma unroll
                for (int m2 = 0; m2 < KK; ++m2) {
                    bool sw = cnd < kd[m2];
                    unsigned long long lo = sw ? cnd : kd[m2];
                    unsigned long long hi = sw ? kd[m2] : cnd;
                    kd[m2] = lo;
                    cnd = hi;
                }
            }
        }
#pragma unroll
        for (int r = 0; r < KK; ++r) {
            unsigned long long c = kd[0];
            unsigned long long wm = c;
#pragma unroll
            for (int d = 1; d < 64; d <<= 1) {
                unsigned long long o = __shfl_xor(wm, d);
                wm = (o < wm) ? o : wm;
            }
            if (lane == r) kout = wm;
            if (c == wm) {
#pragma unroll
                for (int m2 = 0; m2 < KK - 1; ++m2) kd[m2] = kd[m2 + 1];
                kd[KK - 1] = ~0ULL;
            }
        }
    }

    if (lane < KK) {
        out[(size_t)tu * KK + lane] = (int)(kout & 0xFFFFFFFFULL);
        out[(size_t)BB * NN * KK + (size_t)tu * KK + lane] = n;
    }
}

// ===========================================================================
// OLD PATH (verified fallback) -- unchanged
// ===========================================================================
__global__ __launch_bounds__(256) void knorm_kernel(const float* __restrict__ x,
                                                    float* __restrict__ xnT,
                                                    float* __restrict__ sq) {
    int t = blockIdx.x * 256 + threadIdx.x;
    int b = t >> 13;
    int n = t & (NN - 1);
    const float* xb = x + (size_t)b * DD * NN + n;
    float v[DD];
    float ss = 0.0f;
#pragma unroll
    for (int d = 0; d < DD; ++d) {
        v[d] = xb[(size_t)d * NN];
        ss = fmaf(v[d], v[d], ss);
    }
    float norm = sqrtf(ss);
    float inv = 1.0f / fmaxf(norm, 1e-12f);
    float s2 = 0.0f;
#pragma unroll
    for (int d = 0; d < DD; ++d) {
        float xv = v[d] * inv;
        v[d] = xv;
        s2 = fmaf(xv, xv, s2);
    }
    float4* o4 = reinterpret_cast<float4*>(xnT + (size_t)t * DD);
#pragma unroll
    for (int d = 0; d < DD; d += 4) {
        o4[d >> 2] = make_float4(v[d], v[d + 1], v[d + 2], v[d + 3]);
    }
    sq[t] = s2;
}

template <int S>
__global__ __launch_bounds__(256, 2) void kdist_kernel(const float* __restrict__ xnT,
                                                       const float* __restrict__ sq,
                                                       unsigned long long* __restrict__ cand) {
    const int rb = blockIdx.x;
    const int b = rb >> 5;
    const int nbase = (rb & 31) * 256;
    const int n = nbase + threadIdx.x;
    const int s = blockIdx.y;
    const int jcount = NN / S;
    const int j0 = s * jcount;
    const int j1 = j0 + jcount;

    const float* __restrict__ Bb = xnT + ((size_t)b * NN) * DD;
    const float* __restrict__ sqb = sq + (size_t)b * NN;

    float ar[DD];
    {
        const float4* a4 = reinterpret_cast<const float4*>(Bb + (size_t)n * DD);
#pragma unroll
        for (int d = 0; d < DD; d += 4) {
            float4 f = a4[d >> 2];
            ar[d] = f.x; ar[d + 1] = f.y; ar[d + 2] = f.z; ar[d + 3] = f.w;
        }
    }
#pragma unroll
    for (int d = 0; d < DD; ++d) {
        asm volatile("" : "+v"(ar[d]));
    }

    unsigned long long kd[KK];
#pragma unroll
    for (int m = 0; m < KK; ++m) kd[m] = ~0ULL;

#pragma unroll 2
    for (int j = j0; j < j1; ++j) {
        const float4* bc4 = reinterpret_cast<const float4*>(Bb + (size_t)j * DD);
        float a0 = 0.0f, a1 = 0.0f, a2 = 0.0f, a3 = 0.0f;
#pragma unroll
        for (int d4 = 0; d4 < DD / 4; ++d4) {
            float4 f = bc4[d4];
            a0 = fmaf(ar[4 * d4 + 0], f.x, a0);
            a1 = fmaf(ar[4 * d4 + 1], f.y, a1);
            a2 = fmaf(ar[4 * d4 + 2], f.z, a2);
            a3 = fmaf(ar[4 * d4 + 3], f.w, a3);
        }
        float dot = (a0 + a1) + (a2 + a3);
        float key = fmaf(-2.0f, dot, sqb[j]);
        unsigned int ub = __float_as_uint(key);
        ub ^= (0x80000000u | (unsigned int)((int)ub >> 31));
        unsigned long long cnd = ((unsigned long long)ub << 32) | (unsigned int)j;
        if (cnd < kd[KK - 1]) {
#pragma unroll
            for (int m = 0; m < KK; ++m) {
                bool sw = cnd < kd[m];
                unsigned long long lo = sw ? cnd : kd[m];
                unsigned long long hi = sw ? kd[m] : cnd;
                kd[m] = lo;
                cnd = hi;
            }
        }
    }

    unsigned long long* outc = cand + ((size_t)(b * NN + n) * S + s) * KK;
#pragma unroll
    for (int m = 0; m < KK; ++m) outc[m] = kd[m];
}

template <int S>
__global__ __launch_bounds__(256) void kmerge_kernel(const unsigned long long* __restrict__ cand,
                                                     int* __restrict__ out) {
    int t = blockIdx.x * 256 + threadIdx.x;
    const unsigned long long* c = cand + (size_t)t * (S * KK);
    unsigned long long kd[KK];
#pragma unroll
    for (int m = 0; m < KK; ++m) kd[m] = ~0ULL;
#pragma unroll
    for (int q = 0; q < S * KK; ++q) {
        unsigned long long cnd = c[q];
        if (cnd < kd[KK - 1]) {
#pragma unroll
            for (int m = 0; m < KK; ++m) {
                bool sw = cnd < kd[m];
                unsigned long long lo = sw ? cnd : kd[m];
                unsigned long long hi = sw ? kd[m] : cnd;
                kd[m] = lo;
                cnd = hi;
            }
        }
    }
    int n = t & (NN - 1);
    int* out0 = out + (size_t)t * KK;
    int* out1 = out + (size_t)BB * NN * KK + (size_t)t * KK;
#pragma unroll
    for (int m = 0; m < KK; ++m) {
        out0[m] = (int)(kd[m] & 0xFFFFFFFFULL);
        out1[m] = n;
    }
}

extern "C" void kernel_launch(void* const* d_in, const int* in_sizes, int n_in,
                              void* d_out, int out_size, void* d_ws, size_t ws_size,
                              hipStream_t stream) {
    const float* x = (const float*)d_in[0];
    int* out = (int*)d_out;
    char* ws = (char*)d_ws;

    // Shared layout head
    constexpr size_t XNT_B = (size_t)BB * NN * DD * 4;          //  8,388,608
    constexpr size_t SQ_B  = (size_t)BB * NN * 4;               //    131,072
    float* xnT = (float*)ws;
    float* sq  = (float*)(ws + XNT_B);

    // New-path layout (offsets kept from the verified R2 layout; Plo/Slo slots
    // are unused but reserved so NEED_NEW is unchanged)
    constexpr size_t BF_B  = (size_t)BB * NN * DD * 2;          //  4,194,304 each
    constexpr size_t OFF_PHI = XNT_B + SQ_B;
    constexpr size_t OFF_PLO = OFF_PHI + BF_B;
    constexpr size_t OFF_SHI = OFF_PLO + BF_B;
    constexpr size_t OFF_SLO = OFF_SHI + BF_B;
    constexpr size_t OFF_MIN = OFF_SLO + BF_B;
    constexpr size_t MIN_B   = (size_t)512 * BB * NN * 4;       // 67,108,864
    constexpr size_t NEED_NEW = OFF_MIN + MIN_B;                // 92,405,760

    if (ws_size >= NEED_NEW) {
        unsigned short* Phi = (unsigned short*)(ws + OFF_PHI);
        unsigned short* Shi = (unsigned short*)(ws + OFF_SHI);
        float* minbuf = (float*)(ws + OFF_MIN);

        knorm2_kernel<<<dim3(BB * NN / 256), dim3(256), 0, stream>>>(x, xnT, sq, Phi, Shi);
        kmin_kernel<<<dim3(BB * NN / 256, 8), dim3(256), 0, stream>>>(Shi, Phi, minbuf);
        ksel_kernel<<<dim3(BB * NN / 4), dim3(256), 0, stream>>>(xnT, sq, minbuf, Phi, out);
        return;
    }

    // Old verified path
    unsigned long long* cand = (unsigned long long*)(ws + XNT_B + SQ_B);
    const size_t base = XNT_B + SQ_B;
    const size_t need8 = base + (size_t)BB * NN * 8 * KK * 8;

    knorm_kernel<<<dim3(BB * NN / 256), dim3(256), 0, stream>>>(x, xnT, sq);
    if (ws_size >= need8) {
        kdist_kernel<8><<<dim3(BB * NN / 256, 8), dim3(256), 0, stream>>>(xnT, sq, cand);
        kmerge_kernel<8><<<dim3(BB * NN / 256), dim3(256), 0, stream>>>(cand, out);
    } else {
        kdist_kernel<4><<<dim3(BB * NN / 256, 4), dim3(256), 0, stream>>>(xnT, sq, cand);
        kmerge_kernel<4><<<dim3(BB * NN / 256), dim3(256), 0, stream>>>(cand, out);
    }
}

// Round 9
// 247.362 us; speedup vs baseline: 1.5515x; 1.0077x over previous
//
#include <hip/hip_runtime.h>

// Problem constants (fixed by setup_inputs): x (4, 64, 8192, 1) fp32, k=9, dilation=1
#define BB 4
#define DD 64
#define NN 8192
#define KK 9

// ---------------------------------------------------------------------------
// MFMA filter + exact rescan
//   K1 knorm2: normalize, emit fp32 xnT, sq, fp16 casts P=fp16(xn), S=fp16(-2xn)
//   K2 kmin:   fp16 MFMA GEMM -> per-(row, 16-j-group) min of approx -2*dot
//              (minbuf units = "-2*dot"). 64 i-rows/wave (R8). R9: register
//              ping-pong A-prefetch — R8 inference: device MFMA ~3.5us, L2
//              A-traffic ~15us, kernel ~95us => latency-exposed A-loads;
//              load tile tt+1/tt+2 while MFMA consumes tile tt.
//   K3 ksel:   wave-per-row (R6/R8-proven base: readfirstlane row, scalar ar).
//       th9p  = 9th-smallest lane-min (21-stage f32 bitonic)   [R6-proven]
//       theta = th9p + 8e-3 group window (fp32 minbuf units)   [R6-proven]
//       stage1: gather fp16 Phi rows (L2-resident), dot vs fp16 row via
//               v_dot2_f32_f16 (R9). BOTH operands fp16 now:
//               E1 <= 2^-10*||a||*||b||*2scale + accum ~= 2.1e-3.
//               kappa1 = th9p + 6.5e-3 on -2*ap:
//                 top-9 j: m2ap <= th9p + err_mfma(2.5e-3)+dSq(1e-4)+E1 =
//                 th9p+4.7e-3 < kappa1 (margin 1.8e-3). Witnesses: the 9
//                 smallest lane-min groups' argmins have m2ap <= th9p +
//                 err_mfma + E1 = +4.6e-3 < kappa1 => S1 >= 9.
//       stage2: exact fp32 key (fresh xnT row load) for <=64 survivors, ONE
//               21-stage u64 bitonic; byte-identical ordering + tie-break.
//       Fallbacks: cnt>40 groups -> full scan; S1>64 -> exact per-lane kd[9].
// Fallback to the original verified path if ws_size is too small.
// ---------------------------------------------------------------------------

typedef __attribute__((ext_vector_type(8))) _Float16 f16x8;  // 4 VGPR MFMA operand
typedef __attribute__((ext_vector_type(16))) float f32x16;   // 32x32 accumulator
typedef __attribute__((ext_vector_type(2))) _Float16 h2;     // v_dot2 operand
struct H2x4 { h2 a, b, c, d; };

__device__ __forceinline__ uint4 pack8(const unsigned* w) {
    return make_uint4(w[0] | (w[1] << 16), w[2] | (w[3] << 16),
                      w[4] | (w[5] << 16), w[6] | (w[7] << 16));
}

__device__ __forceinline__ float min3f(float a, float b, float c) {
    return fminf(fminf(a, b), c);            // clang fuses to v_min3_f32
}

__device__ __forceinline__ float dot2acc(h2 g, h2 r, float acc) {
#if __has_builtin(__builtin_amdgcn_fdot2)
    return __builtin_amdgcn_fdot2(g, r, acc, false);
#else
    acc = fmaf((float)g[0], (float)r[0], acc);
    return fmaf((float)g[1], (float)r[1], acc);
#endif
}

// ---------------- K1: normalize + fp32 pack + sq + fp16 casts -----------------
__global__ __launch_bounds__(256) void knorm2_kernel(const float* __restrict__ x,
                                                     float* __restrict__ xnT,
                                                     float* __restrict__ sq,
                                                     unsigned short* __restrict__ Phi,
                                                     unsigned short* __restrict__ Shi) {
    int t = blockIdx.x * 256 + threadIdx.x;      // row id 0..B*N-1
    int b = t >> 13;
    int n = t & (NN - 1);
    const float* xb = x + (size_t)b * DD * NN + n;
    float v[DD];
    float ss = 0.0f;
#pragma unroll
    for (int d = 0; d < DD; ++d) {
        v[d] = xb[(size_t)d * NN];
        ss = fmaf(v[d], v[d], ss);
    }
    float inv = 1.0f / fmaxf(sqrtf(ss), 1e-12f);
    float s2 = 0.0f;
#pragma unroll
    for (int d = 0; d < DD; ++d) {
        v[d] *= inv;
        s2 = fmaf(v[d], v[d], s2);
    }
    sq[t] = s2;
    float4* o4 = reinterpret_cast<float4*>(xnT + (size_t)t * DD);
#pragma unroll
    for (int d = 0; d < DD; d += 4) o4[d >> 2] = make_float4(v[d], v[d+1], v[d+2], v[d+3]);

    size_t base = (size_t)t * DD;
#pragma unroll
    for (int d0 = 0; d0 < DD; d0 += 8) {
        unsigned ph[8], sh[8];
#pragma unroll
        for (int e = 0; e < 8; ++e) {
            float f = v[d0 + e];
            _Float16 hp = (_Float16)f;               // v_cvt_f16_f32 (RNE)
            _Float16 hs = (_Float16)(-2.0f * f);     // exact scale before rounding
            ph[e] = (unsigned)__builtin_bit_cast(unsigned short, hp);
            sh[e] = (unsigned)__builtin_bit_cast(unsigned short, hs);
        }
        *reinterpret_cast<uint4*>(Phi + base + d0) = pack8(ph);
        *reinterpret_cast<uint4*>(Shi + base + d0) = pack8(sh);
    }
}

// ---------------- K2: MFMA min pass (fp16, 64 rows/wave, A-prefetch) ---------
// Wave = 64 i-rows (two B-fragment sets share each A tile: 8 MFMA / 4 loads);
// block = 4 waves = 256 rows; grid (128 rowblocks, 8 jsplits), 32 tiles/wave.
// R9: ping-pong A0/A1 register buffers — issue next tile's loads before the
// current tile's MFMA chain so L2 latency hides under compute.
__global__ __launch_bounds__(256, 4) void kmin_kernel(const unsigned short* __restrict__ Shi,
                                                      const unsigned short* __restrict__ Phi,
                                                      float* __restrict__ minbuf) {
    __shared__ float stage[4][64][33];                  // 33.8 KB/block
    const int lane = threadIdx.x & 63;
    const int wave = threadIdx.x >> 6;
    const int l31 = lane & 31;
    const int half = lane >> 5;
    const int i0 = blockIdx.x * 256 + wave * 64;        // global i-row base
    const int b = i0 >> 13;                             // 256 | 8192 -> uniform
    const int jloc0 = blockIdx.y * (NN / 8);            // batch-local j start
    const int goff = jloc0 >> 5;                        // tile base (32 per split)

    f16x8 Bh0[4], Bh1[4];
    {
        const size_t ib0 = (size_t)(i0 + l31) * DD + half * 8;
        const size_t ib1 = (size_t)(i0 + 32 + l31) * DD + half * 8;
#pragma unroll
        for (int kc = 0; kc < 4; ++kc) {
            Bh0[kc] = *reinterpret_cast<const f16x8*>(Phi + ib0 + kc * 16);
            Bh1[kc] = *reinterpret_cast<const f16x8*>(Phi + ib1 + kc * 16);
        }
    }
    const size_t ja0 = ((size_t)b * NN + jloc0 + l31) * DD + half * 8;

    f16x8 A0[4], A1[4];
#pragma unroll
    for (int kc = 0; kc < 4; ++kc)
        A0[kc] = *reinterpret_cast<const f16x8*>(Shi + ja0 + kc * 16);

#pragma unroll 2
    for (int u2 = 0; u2 < 16; ++u2) {
        const int t0 = u2 * 2;                          // even tile
        {   // prefetch odd tile
            const size_t ja = ja0 + (size_t)(t0 + 1) * 32 * DD;
#pragma unroll
            for (int kc = 0; kc < 4; ++kc)
                A1[kc] = *reinterpret_cast<const f16x8*>(Shi + ja + kc * 16);
        }
        {   // consume even tile (A0)
            f32x16 c0 = {}, c1 = {};
#pragma unroll
            for (int kc = 0; kc < 4; ++kc)
                c0 = __builtin_amdgcn_mfma_f32_32x32x16_f16(A0[kc], Bh0[kc], c0, 0, 0, 0);
#pragma unroll
            for (int kc = 0; kc < 4; ++kc)
                c1 = __builtin_amdgcn_mfma_f32_32x32x16_f16(A0[kc], Bh1[kc], c1, 0, 0, 0);
            const int col = half * 16 + (t0 & 15);
            {
                float q0 = min3f(c0[0], c0[1], c0[2]);
                float q1 = min3f(c0[3], c0[4], c0[5]);
                float q2 = min3f(c0[6], c0[7], c0[8]);
                float q3 = min3f(c0[9], c0[10], c0[11]);
                float q4 = min3f(c0[12], c0[13], c0[14]);
                stage[wave][l31][col] = fminf(min3f(q0, q1, q2), min3f(q3, q4, c0[15]));
            }
            {
                float q0 = min3f(c1[0], c1[1], c1[2]);
                float q1 = min3f(c1[3], c1[4], c1[5]);
                float q2 = min3f(c1[6], c1[7], c1[8]);
                float q3 = min3f(c1[9], c1[10], c1[11]);
                float q4 = min3f(c1[12], c1[13], c1[14]);
                stage[wave][32 + l31][col] = fminf(min3f(q0, q1, q2), min3f(q3, q4, c1[15]));
            }
        }
        if (u2 < 15) {  // prefetch next even tile
            const size_t ja = ja0 + (size_t)(t0 + 2) * 32 * DD;
#pragma unroll
            for (int kc = 0; kc < 4; ++kc)
                A0[kc] = *reinterpret_cast<const f16x8*>(Shi + ja + kc * 16);
        }
        {   // consume odd tile (A1)
            f32x16 c0 = {}, c1 = {};
#pragma unroll
            for (int kc = 0; kc < 4; ++kc)
                c0 = __builtin_amdgcn_mfma_f32_32x32x16_f16(A1[kc], Bh0[kc], c0, 0, 0, 0);
#pragma unroll
            for (int kc = 0; kc < 4; ++kc)
                c1 = __builtin_amdgcn_mfma_f32_32x32x16_f16(A1[kc], Bh1[kc], c1, 0, 0, 0);
            const int col = half * 16 + ((t0 + 1) & 15);
            {
                float q0 = min3f(c0[0], c0[1], c0[2]);
                float q1 = min3f(c0[3], c0[4], c0[5]);
                float q2 = min3f(c0[6], c0[7], c0[8]);
                float q3 = min3f(c0[9], c0[10], c0[11]);
                float q4 = min3f(c0[12], c0[13], c0[14]);
                stage[wave][l31][col] = fminf(min3f(q0, q1, q2), min3f(q3, q4, c0[15]));
            }
            {
                float q0 = min3f(c1[0], c1[1], c1[2]);
                float q1 = min3f(c1[3], c1[4], c1[5]);
                float q2 = min3f(c1[6], c1[7], c1[8]);
                float q3 = min3f(c1[9], c1[10], c1[11]);
                float q4 = min3f(c1[12], c1[13], c1[14]);
                stage[wave][32 + l31][col] = fminf(min3f(q0, q1, q2), min3f(q3, q4, c1[15]));
            }
        }
        if ((t0 & 15) == 14) {  // tiles 15 / 31 done -> flush half
            const int f = t0 >> 4;
            const int gbase = goff + f * 16;
#pragma unroll
            for (int it = 0; it < 8; ++it) {
                int idx = it * 64 + lane;                // 0..511
                int c4 = idx & 3;
                int hf = (idx >> 2) & 1;
                int r = idx >> 3;                        // 0..63
                const float* s = &stage[wave][r][hf * 16 + c4 * 4];
                float4 vv = make_float4(s[0], s[1], s[2], s[3]);
                *reinterpret_cast<float4*>(minbuf + (size_t)(i0 + r) * 512 +
                                           hf * 256 + gbase + c4 * 4) = vv;
            }
        }
    }
}

// ---------------- K3: wave-per-row, bitonic theta + two-stage rescan ---------
__global__ __launch_bounds__(256) void ksel_kernel(const float* __restrict__ xnT,
                                                   const float* __restrict__ sq,
                                                   const float* __restrict__ minbuf,
                                                   const unsigned short* __restrict__ Phi,
                                                   int* __restrict__ out) {
    __shared__ unsigned short glist[4][40];
    __shared__ unsigned short jlist[4][64];
    const int lane = threadIdx.x & 63;
    const int wave = threadIdx.x >> 6;
    const int t = blockIdx.x * 4 + wave;                 // row id
    const int tu = __builtin_amdgcn_readfirstlane(t);    // wave-uniform row
    const int b = tu >> 13;
    const int n = tu & (NN - 1);

    // lane's 8 group-mins (coalesced: 2KB contiguous per wave)
    float gm[8];
    {
        const float4* m4 = reinterpret_cast<const float4*>(minbuf + (size_t)tu * 512 + lane * 8);
        float4 a = m4[0], c = m4[1];
        gm[0] = a.x; gm[1] = a.y; gm[2] = a.z; gm[3] = a.w;
        gm[4] = c.x; gm[5] = c.y; gm[6] = c.z; gm[7] = c.w;
    }

    // th9p: bitonic-sort the 64 lane-mins (ascending); lane 8 holds 9th-smallest
    float sv = fminf(min3f(gm[0], gm[1], gm[2]),
                     fminf(min3f(gm[3], gm[4], gm[5]), fminf(gm[6], gm[7])));
#pragma unroll
    for (int k = 2; k <= 64; k <<= 1) {
#pragma unroll
        for (int jj = k >> 1; jj >= 1; jj >>= 1) {
            float o = __shfl_xor(sv, jj);
            bool keepMin = (((lane & jj) == 0) == ((lane & k) == 0));
            sv = keepMin ? fminf(sv, o) : fmaxf(sv, o);
        }
    }
    const float th9p = __shfl(sv, 8);
    const float theta  = th9p + 8e-3f;     // group window (fp32 minbuf, R6-proven)
    const float kappa1 = th9p + 6.5e-3f;   // stage-1 cutoff (both-fp16 dot, R9 bound)

    // ballot-compact candidate groups into wave-private LDS list
    int cnt = 0;
    unsigned short* gl = &glist[wave][0];
#pragma unroll
    for (int q = 0; q < 8; ++q) {
        bool c = gm[q] <= theta;
        unsigned long long mask = __ballot(c);
        int pos = cnt + __popcll(mask & ((1ULL << lane) - 1ULL));
        if (c && pos < 40) gl[pos] = (unsigned short)(lane * 8 + q);
        cnt += (int)__popcll(mask);
    }
    __syncthreads();

    // fp16 row for stage-1 (wave-uniform address -> scalar loads)
    const unsigned short* __restrict__ Pb = Phi + ((size_t)b * NN) * DD;
    H2x4 arh[8];
    {
        const f16x8* pr = reinterpret_cast<const f16x8*>(Phi + (size_t)tu * DD);
#pragma unroll
        for (int c8 = 0; c8 < 8; ++c8) arh[c8] = __builtin_bit_cast(H2x4, pr[c8]);
    }

    // ---- stage 1: fp16-row gather (L2-resident) + v_dot2 filter -------------
    const bool ovf = (cnt > 40);
    const int total = ovf ? NN : cnt * 16;
    const int nIt = (total + 63) >> 6;
    int S1 = 0;
    unsigned short* jl = &jlist[wave][0];
#pragma unroll 1
    for (int m = 0; m < nIt; ++m) {
        const int idx = m * 64 + lane;
        const bool act = idx < total;
        float m2ap = __uint_as_float(0x7f800000u);
        int j = 0;
        if (act) {
            if (ovf) {
                j = idx;
            } else {
                int g = (int)gl[idx >> 4];
                int s4 = idx & 15;
                j = (g & 255) * 32 + ((s4 >> 2) * 8) + ((g >> 8) * 4) + (s4 & 3);
            }
            const f16x8* p8 = reinterpret_cast<const f16x8*>(Pb + (size_t)j * DD);
            float a0 = 0.0f, a1 = 0.0f, a2 = 0.0f, a3 = 0.0f;
#pragma unroll
            for (int c8 = 0; c8 < 8; ++c8) {
                H2x4 g2 = __builtin_bit_cast(H2x4, p8[c8]);
                a0 = dot2acc(g2.a, arh[c8].a, a0);
                a1 = dot2acc(g2.b, arh[c8].b, a1);
                a2 = dot2acc(g2.c, arh[c8].c, a2);
                a3 = dot2acc(g2.d, arh[c8].d, a3);
            }
            m2ap = -2.0f * ((a0 + a1) + (a2 + a3));
        }
        bool pass = act && (m2ap <= kappa1);
        unsigned long long mask = __ballot(pass);
        int pos = S1 + __popcll(mask & ((1ULL << lane) - 1ULL));
        if (pass && pos < 64) jl[pos] = (unsigned short)j;
        S1 += (int)__popcll(mask);
    }
    __syncthreads();

    // exact fp32 row (loaded after stage-1 so arh SGPRs can retire)
    const float* __restrict__ Bb = xnT + (size_t)b * NN * DD;
    const float* __restrict__ sqb = sq + (size_t)b * NN;
    float ar[DD];
    {
        const float4* a4 = reinterpret_cast<const float4*>(xnT + (size_t)tu * DD);
#pragma unroll
        for (int d = 0; d < DD; d += 4) {
            float4 f = a4[d >> 2];
            ar[d] = f.x; ar[d + 1] = f.y; ar[d + 2] = f.z; ar[d + 3] = f.w;
        }
    }

    unsigned long long kout = ~0ULL;
    if (S1 <= 64) {
        // ---- stage 2: exact fp32 keys for survivors + ONE u64 bitonic -------
        unsigned long long v = ~0ULL;
        if (lane < S1) {
            int j = (int)jl[lane];
            const float4* bc4 = reinterpret_cast<const float4*>(Bb + (size_t)j * DD);
            float a0 = 0.0f, a1 = 0.0f, a2 = 0.0f, a3 = 0.0f;
#pragma unroll
            for (int d4 = 0; d4 < DD / 4; ++d4) {
                float4 f = bc4[d4];
                a0 = fmaf(ar[4 * d4 + 0], f.x, a0);
                a1 = fmaf(ar[4 * d4 + 1], f.y, a1);
                a2 = fmaf(ar[4 * d4 + 2], f.z, a2);
                a3 = fmaf(ar[4 * d4 + 3], f.w, a3);
            }
            float dot = (a0 + a1) + (a2 + a3);
            float key = fmaf(-2.0f, dot, sqb[j]);        // byte-identical ordering key
            unsigned ub = __float_as_uint(key);
            ub ^= (0x80000000u | (unsigned)((int)ub >> 31));
            v = ((unsigned long long)ub << 32) | (unsigned)j;
        }
#pragma unroll
        for (int k = 2; k <= 64; k <<= 1) {
#pragma unroll
            for (int jj = k >> 1; jj >= 1; jj >>= 1) {
                unsigned long long o = __shfl_xor(v, jj);
                bool keepMin = (((lane & jj) == 0) == ((lane & k) == 0));
                bool less = o < v;
                unsigned long long mn = less ? o : v;
                unsigned long long mx = less ? v : o;
                v = keepMin ? mn : mx;
            }
        }
        kout = v;
    } else {
        // rare: exact per-lane kd[9] + 9-round butterfly over the candidate set
        unsigned long long kd[KK];
#pragma unroll
        for (int m = 0; m < KK; ++m) kd[m] = ~0ULL;
#pragma unroll 1
        for (int m = 0; m < nIt; ++m) {
            const int idx = m * 64 + lane;
            if (idx >= total) continue;
            int j;
            if (ovf) {
                j = idx;
            } else {
                int g = (int)gl[idx >> 4];
                int s4 = idx & 15;
                j = (g & 255) * 32 + ((s4 >> 2) * 8) + ((g >> 8) * 4) + (s4 & 3);
            }
            const float4* bc4 = reinterpret_cast<const float4*>(Bb + (size_t)j * DD);
            float a0 = 0.0f, a1 = 0.0f, a2 = 0.0f, a3 = 0.0f;
#pragma unroll
            for (int d4 = 0; d4 < DD / 4; ++d4) {
                float4 f = bc4[d4];
                a0 = fmaf(ar[4 * d4 + 0], f.x, a0);
                a1 = fmaf(ar[4 * d4 + 1], f.y, a1);
                a2 = fmaf(ar[4 * d4 + 2], f.z, a2);
                a3 = fmaf(ar[4 * d4 + 3], f.w, a3);
            }
            float dot = (a0 + a1) + (a2 + a3);
            float key = fmaf(-2.0f, dot, sqb[j]);
            unsigned ub = __float_as_uint(key);
            ub ^= (0x80000000u | (unsigned)((int)ub >> 31));
            unsigned long long cnd = ((unsigned long long)ub << 32) | (unsigned)j;
            if (cnd < kd[KK - 1]) {
#pragma unroll
                for (int m2 = 0; m2 < KK; ++m2) {
                    bool sw = cnd < kd[m2];
                    unsigned long long lo = sw ? cnd : kd[m2];
                    unsigned long long hi = sw ? kd[m2] : cnd;
                    kd[m2] = lo;
                    cnd = hi;
                }
            }
        }
#pragma unroll
        for (int r = 0; r < KK; ++r) {
            unsigned long long c = kd[0];
            unsigned long long wm = c;
#pragma unroll
            for (int d = 1; d < 64; d <<= 1) {
                unsigned long long o = __shfl_xor(wm, d);
                wm = (o < wm) ? o : wm;
            }
            if (lane == r) kout = wm;
            if (c == wm) {
#pragma unroll
                for (int m2 = 0; m2 < KK - 1; ++m2) kd[m2] = kd[m2 + 1];
                kd[KK - 1] = ~0ULL;
            }
        }
    }

    if (lane < KK) {
        out[(size_t)tu * KK + lane] = (int)(kout & 0xFFFFFFFFULL);
        out[(size_t)BB * NN * KK + (size_t)tu * KK + lane] = n;
    }
}

// ===========================================================================
// OLD PATH (verified fallback) -- unchanged
// ===========================================================================
__global__ __launch_bounds__(256) void knorm_kernel(const float* __restrict__ x,
                                                    float* __restrict__ xnT,
                                                    float* __restrict__ sq) {
    int t = blockIdx.x * 256 + threadIdx.x;
    int b = t >> 13;
    int n = t & (NN - 1);
    const float* xb = x + (size_t)b * DD * NN + n;
    float v[DD];
    float ss = 0.0f;
#pragma unroll
    for (int d = 0; d < DD; ++d) {
        v[d] = xb[(size_t)d * NN];
        ss = fmaf(v[d], v[d], ss);
    }
    float norm = sqrtf(ss);
    float inv = 1.0f / fmaxf(norm, 1e-12f);
    float s2 = 0.0f;
#pragma unroll
    for (int d = 0; d < DD; ++d) {
        float xv = v[d] * inv;
        v[d] = xv;
        s2 = fmaf(xv, xv, s2);
    }
    float4* o4 = reinterpret_cast<float4*>(xnT + (size_t)t * DD);
#pragma unroll
    for (int d = 0; d < DD; d += 4) {
        o4[d >> 2] = make_float4(v[d], v[d + 1], v[d + 2], v[d + 3]);
    }
    sq[t] = s2;
}

template <int S>
__global__ __launch_bounds__(256, 2) void kdist_kernel(const float* __restrict__ xnT,
                                                       const float* __restrict__ sq,
                                                       unsigned long long* __restrict__ cand) {
    const int rb = blockIdx.x;
    const int b = rb >> 5;
    const int nbase = (rb & 31) * 256;
    const int n = nbase + threadIdx.x;
    const int s = blockIdx.y;
    const int jcount = NN / S;
    const int j0 = s * jcount;
    const int j1 = j0 + jcount;

    const float* __restrict__ Bb = xnT + ((size_t)b * NN) * DD;
    const float* __restrict__ sqb = sq + (size_t)b * NN;

    float ar[DD];
    {
        const float4* a4 = reinterpret_cast<const float4*>(Bb + (size_t)n * DD);
#pragma unroll
        for (int d = 0; d < DD; d += 4) {
            float4 f = a4[d >> 2];
            ar[d] = f.x; ar[d + 1] = f.y; ar[d + 2] = f.z; ar[d + 3] = f.w;
        }
    }
#pragma unroll
    for (int d = 0; d < DD; ++d) {
        asm volatile("" : "+v"(ar[d]));
    }

    unsigned long long kd[KK];
#pragma unroll
    for (int m = 0; m < KK; ++m) kd[m] = ~0ULL;

#pragma unroll 2
    for (int j = j0; j < j1; ++j) {
        const float4* bc4 = reinterpret_cast<const float4*>(Bb + (size_t)j * DD);
        float a0 = 0.0f, a1 = 0.0f, a2 = 0.0f, a3 = 0.0f;
#pragma unroll
        for (int d4 = 0; d4 < DD / 4; ++d4) {
            float4 f = bc4[d4];
            a0 = fmaf(ar[4 * d4 + 0], f.x, a0);
            a1 = fmaf(ar[4 * d4 + 1], f.y, a1);
            a2 = fmaf(ar[4 * d4 + 2], f.z, a2);
            a3 = fmaf(ar[4 * d4 + 3], f.w, a3);
        }
        float dot = (a0 + a1) + (a2 + a3);
        float key = fmaf(-2.0f, dot, sqb[j]);
        unsigned int ub = __float_as_uint(key);
        ub ^= (0x80000000u | (unsigned int)((int)ub >> 31));
        unsigned long long cnd = ((unsigned long long)ub << 32) | (unsigned int)j;
        if (cnd < kd[KK - 1]) {
#pragma unroll
            for (int m = 0; m < KK; ++m) {
                bool sw = cnd < kd[m];
                unsigned long long lo = sw ? cnd : kd[m];
                unsigned long long hi = sw ? kd[m] : cnd;
                kd[m] = lo;
                cnd = hi;
            }
        }
    }

    unsigned long long* outc = cand + ((size_t)(b * NN + n) * S + s) * KK;
#pragma unroll
    for (int m = 0; m < KK; ++m) outc[m] = kd[m];
}

template <int S>
__global__ __launch_bounds__(256) void kmerge_kernel(const unsigned long long* __restrict__ cand,
                                                     int* __restrict__ out) {
    int t = blockIdx.x * 256 + threadIdx.x;
    const unsigned long long* c = cand + (size_t)t * (S * KK);
    unsigned long long kd[KK];
#pragma unroll
    for (int m = 0; m < KK; ++m) kd[m] = ~0ULL;
#pragma unroll
    for (int q = 0; q < S * KK; ++q) {
        unsigned long long cnd = c[q];
        if (cnd < kd[KK - 1]) {
#pragma unroll
            for (int m = 0; m < KK; ++m) {
                bool sw = cnd < kd[m];
                unsigned long long lo = sw ? cnd : kd[m];
                unsigned long long hi = sw ? kd[m] : cnd;
                kd[m] = lo;
                cnd = hi;
            }
        }
    }
    int n = t & (NN - 1);
    int* out0 = out + (size_t)t * KK;
    int* out1 = out + (size_t)BB * NN * KK + (size_t)t * KK;
#pragma unroll
    for (int m = 0; m < KK; ++m) {
        out0[m] = (int)(kd[m] & 0xFFFFFFFFULL);
        out1[m] = n;
    }
}

extern "C" void kernel_launch(void* const* d_in, const int* in_sizes, int n_in,
                              void* d_out, int out_size, void* d_ws, size_t ws_size,
                              hipStream_t stream) {
    const float* x = (const float*)d_in[0];
    int* out = (int*)d_out;
    char* ws = (char*)d_ws;

    // Shared layout head
    constexpr size_t XNT_B = (size_t)BB * NN * DD * 4;          //  8,388,608
    constexpr size_t SQ_B  = (size_t)BB * NN * 4;               //    131,072
    float* xnT = (float*)ws;
    float* sq  = (float*)(ws + XNT_B);

    // New-path layout (offsets kept from the verified R2 layout; Plo/Slo slots
    // are unused but reserved so NEED_NEW is unchanged)
    constexpr size_t BF_B  = (size_t)BB * NN * DD * 2;          //  4,194,304 each
    constexpr size_t OFF_PHI = XNT_B + SQ_B;
    constexpr size_t OFF_PLO = OFF_PHI + BF_B;
    constexpr size_t OFF_SHI = OFF_PLO + BF_B;
    constexpr size_t OFF_SLO = OFF_SHI + BF_B;
    constexpr size_t OFF_MIN = OFF_SLO + BF_B;
    constexpr size_t MIN_B   = (size_t)512 * BB * NN * 4;       // 67,108,864
    constexpr size_t NEED_NEW = OFF_MIN + MIN_B;                // 92,405,760

    if (ws_size >= NEED_NEW) {
        unsigned short* Phi = (unsigned short*)(ws + OFF_PHI);
        unsigned short* Shi = (unsigned short*)(ws + OFF_SHI);
        float* minbuf = (float*)(ws + OFF_MIN);

        knorm2_kernel<<<dim3(BB * NN / 256), dim3(256), 0, stream>>>(x, xnT, sq, Phi, Shi);
        kmin_kernel<<<dim3(BB * NN / 256, 8), dim3(256), 0, stream>>>(Shi, Phi, minbuf);
        ksel_kernel<<<dim3(BB * NN / 4), dim3(256), 0, stream>>>(xnT, sq, minbuf, Phi, out);
        return;
    }

    // Old verified path
    unsigned long long* cand = (unsigned long long*)(ws + XNT_B + SQ_B);
    const size_t base = XNT_B + SQ_B;
    const size_t need8 = base + (size_t)BB * NN * 8 * KK * 8;

    knorm_kernel<<<dim3(BB * NN / 256), dim3(256), 0, stream>>>(x, xnT, sq);
    if (ws_size >= need8) {
        kdist_kernel<8><<<dim3(BB * NN / 256, 8), dim3(256), 0, stream>>>(xnT, sq, cand);
        kmerge_kernel<8><<<dim3(BB * NN / 256), dim3(256), 0, stream>>>(cand, out);
    } else {
        kdist_kernel<4><<<dim3(BB * NN / 256, 4), dim3(256), 0, stream>>>(xnT, sq, cand);
        kmerge_kernel<4><<<dim3(BB * NN / 256), dim3(256), 0, stream>>>(cand, out);
    }
}

// Round 10
// 245.595 us; speedup vs baseline: 1.5627x; 1.0072x over previous
//
#include <hip/hip_runtime.h>

// Problem constants (fixed by setup_inputs): x (4, 64, 8192, 1) fp32, k=9, dilation=1
#define BB 4
#define DD 64
#define NN 8192
#define KK 9

// ---------------------------------------------------------------------------
// MFMA filter + exact rescan
//   K1 knorm2: normalize, emit fp32 xnT, sq, fp16 casts P=fp16(xn), S=fp16(-2xn)
//   K2 kmin:   fp16 MFMA GEMM -> per-(row, 16-j-group) min of approx -2*dot.
//              R10: minbuf stored as FP16 (RNE), storage index
//                s = jsplit*64 + fph*32 + half*16 + u   (fph = 16-tile phase)
//              so each flush writes ONE full 64B line per row (R2 lesson:
//              full-line stores only). Traffic 64->32 MB each way.
//   K3 ksel:   wave-per-row (R6/R8 base: readfirstlane row, scalar ar).
//       th9p' = 9th-smallest lane-min of fp16 gm (21-stage bitonic)
//       theta = th9p' + 8e-3 group window. fp16-quant bound (|v|<=2 => quant
//               <=1e-3): top-9's group-min' <= th9p' + err_mfma(2.5e-3) +
//               dSq(1e-4) + 2*quant = +4.6e-3 < theta (margin 3.4e-3).
//       stage1: fp16 Phi gather + v_dot2; kappa1 = th9p' + 7.5e-3 on -2*ap:
//               top-9: m2ap <= th9p' + quant + err_mfma + E1(2.1e-3) = +5.7e-3
//               < kappa1 (margin 1.8e-3); S1>=9 witnesses at +5.6e-3. 
//       stage2: exact fp32 keys for <=64 survivors, ONE u64 bitonic
//               (byte-identical ordering + tie-break).
//       Fallbacks: cnt>40 groups -> full scan; S1>64 -> exact per-lane kd[9].
// Fallback to the original verified path if ws_size is too small.
// ---------------------------------------------------------------------------

typedef __attribute__((ext_vector_type(8))) _Float16 f16x8;  // 4 VGPR MFMA operand
typedef __attribute__((ext_vector_type(16))) float f32x16;   // 32x32 accumulator
typedef __attribute__((ext_vector_type(2))) _Float16 h2;     // v_dot2 operand
struct H2x4 { h2 a, b, c, d; };

__device__ __forceinline__ uint4 pack8(const unsigned* w) {
    return make_uint4(w[0] | (w[1] << 16), w[2] | (w[3] << 16),
                      w[4] | (w[5] << 16), w[6] | (w[7] << 16));
}

__device__ __forceinline__ float min3f(float a, float b, float c) {
    return fminf(fminf(a, b), c);            // clang fuses to v_min3_f32
}

__device__ __forceinline__ float dot2acc(h2 g, h2 r, float acc) {
#if __has_builtin(__builtin_amdgcn_fdot2)
    return __builtin_amdgcn_fdot2(g, r, acc, false);
#else
    acc = fmaf((float)g[0], (float)r[0], acc);
    return fmaf((float)g[1], (float)r[1], acc);
#endif
}

// storage-index -> j base mapping: s = jsplit*64 + fph*32 + half*16 + u
// tile T = jsplit*32 + fph*16 + u ; j = T*32 + (s4>>2)*8 + half*4 + (s4&3)
__device__ __forceinline__ int s_to_j(int g, int s4) {
    int T = ((g >> 6) << 5) + (((g >> 5) & 1) << 4) + (g & 15);
    return T * 32 + ((s4 >> 2) << 3) + (((g >> 4) & 1) << 2) + (s4 & 3);
}

// ---------------- K1: normalize + fp32 pack + sq + fp16 casts -----------------
__global__ __launch_bounds__(256) void knorm2_kernel(const float* __restrict__ x,
                                                     float* __restrict__ xnT,
                                                     float* __restrict__ sq,
                                                     unsigned short* __restrict__ Phi,
                                                     unsigned short* __restrict__ Shi) {
    int t = blockIdx.x * 256 + threadIdx.x;      // row id 0..B*N-1
    int b = t >> 13;
    int n = t & (NN - 1);
    const float* xb = x + (size_t)b * DD * NN + n;
    float v[DD];
    float ss = 0.0f;
#pragma unroll
    for (int d = 0; d < DD; ++d) {
        v[d] = xb[(size_t)d * NN];
        ss = fmaf(v[d], v[d], ss);
    }
    float inv = 1.0f / fmaxf(sqrtf(ss), 1e-12f);
    float s2 = 0.0f;
#pragma unroll
    for (int d = 0; d < DD; ++d) {
        v[d] *= inv;
        s2 = fmaf(v[d], v[d], s2);
    }
    sq[t] = s2;
    float4* o4 = reinterpret_cast<float4*>(xnT + (size_t)t * DD);
#pragma unroll
    for (int d = 0; d < DD; d += 4) o4[d >> 2] = make_float4(v[d], v[d+1], v[d+2], v[d+3]);

    size_t base = (size_t)t * DD;
#pragma unroll
    for (int d0 = 0; d0 < DD; d0 += 8) {
        unsigned ph[8], sh[8];
#pragma unroll
        for (int e = 0; e < 8; ++e) {
            float f = v[d0 + e];
            _Float16 hp = (_Float16)f;               // v_cvt_f16_f32 (RNE)
            _Float16 hs = (_Float16)(-2.0f * f);     // exact scale before rounding
            ph[e] = (unsigned)__builtin_bit_cast(unsigned short, hp);
            sh[e] = (unsigned)__builtin_bit_cast(unsigned short, hs);
        }
        *reinterpret_cast<uint4*>(Phi + base + d0) = pack8(ph);
        *reinterpret_cast<uint4*>(Shi + base + d0) = pack8(sh);
    }
}

// ---------------- K2: MFMA min pass (fp16, 64 rows/wave, fp16 minbuf) --------
// Wave = 64 i-rows (two B-fragment sets share each A tile: 8 MFMA / 4 loads);
// block = 4 waves = 256 rows; grid (128 rowblocks, 8 jsplits), 32 tiles/wave.
// Ping-pong A prefetch (R9). Mins staged fp32 in wave-private LDS [64][33],
// converted to fp16 at flush and written as ONE 64B line per row per phase.
__global__ __launch_bounds__(256, 4) void kmin_kernel(const unsigned short* __restrict__ Shi,
                                                      const unsigned short* __restrict__ Phi,
                                                      unsigned short* __restrict__ minbuf16) {
    __shared__ float stage[4][64][33];                  // 33.8 KB/block
    const int lane = threadIdx.x & 63;
    const int wave = threadIdx.x >> 6;
    const int l31 = lane & 31;
    const int half = lane >> 5;
    const int i0 = blockIdx.x * 256 + wave * 64;        // global i-row base
    const int b = i0 >> 13;                             // 256 | 8192 -> uniform
    const int jloc0 = blockIdx.y * (NN / 8);            // batch-local j start

    f16x8 Bh0[4], Bh1[4];
    {
        const size_t ib0 = (size_t)(i0 + l31) * DD + half * 8;
        const size_t ib1 = (size_t)(i0 + 32 + l31) * DD + half * 8;
#pragma unroll
        for (int kc = 0; kc < 4; ++kc) {
            Bh0[kc] = *reinterpret_cast<const f16x8*>(Phi + ib0 + kc * 16);
            Bh1[kc] = *reinterpret_cast<const f16x8*>(Phi + ib1 + kc * 16);
        }
    }
    const size_t ja0 = ((size_t)b * NN + jloc0 + l31) * DD + half * 8;

    f16x8 A0[4], A1[4];
#pragma unroll
    for (int kc = 0; kc < 4; ++kc)
        A0[kc] = *reinterpret_cast<const f16x8*>(Shi + ja0 + kc * 16);

#pragma unroll 2
    for (int u2 = 0; u2 < 16; ++u2) {
        const int t0 = u2 * 2;                          // even tile
        {   // prefetch odd tile
            const size_t ja = ja0 + (size_t)(t0 + 1) * 32 * DD;
#pragma unroll
            for (int kc = 0; kc < 4; ++kc)
                A1[kc] = *reinterpret_cast<const f16x8*>(Shi + ja + kc * 16);
        }
        {   // consume even tile (A0)
            f32x16 c0 = {}, c1 = {};
#pragma unroll
            for (int kc = 0; kc < 4; ++kc)
                c0 = __builtin_amdgcn_mfma_f32_32x32x16_f16(A0[kc], Bh0[kc], c0, 0, 0, 0);
#pragma unroll
            for (int kc = 0; kc < 4; ++kc)
                c1 = __builtin_amdgcn_mfma_f32_32x32x16_f16(A0[kc], Bh1[kc], c1, 0, 0, 0);
            const int col = half * 16 + (t0 & 15);
            {
                float q0 = min3f(c0[0], c0[1], c0[2]);
                float q1 = min3f(c0[3], c0[4], c0[5]);
                float q2 = min3f(c0[6], c0[7], c0[8]);
                float q3 = min3f(c0[9], c0[10], c0[11]);
                float q4 = min3f(c0[12], c0[13], c0[14]);
                stage[wave][l31][col] = fminf(min3f(q0, q1, q2), min3f(q3, q4, c0[15]));
            }
            {
                float q0 = min3f(c1[0], c1[1], c1[2]);
                float q1 = min3f(c1[3], c1[4], c1[5]);
                float q2 = min3f(c1[6], c1[7], c1[8]);
                float q3 = min3f(c1[9], c1[10], c1[11]);
                float q4 = min3f(c1[12], c1[13], c1[14]);
                stage[wave][32 + l31][col] = fminf(min3f(q0, q1, q2), min3f(q3, q4, c1[15]));
            }
        }
        if (u2 < 15) {  // prefetch next even tile
            const size_t ja = ja0 + (size_t)(t0 + 2) * 32 * DD;
#pragma unroll
            for (int kc = 0; kc < 4; ++kc)
                A0[kc] = *reinterpret_cast<const f16x8*>(Shi + ja + kc * 16);
        }
        {   // consume odd tile (A1)
            f32x16 c0 = {}, c1 = {};
#pragma unroll
            for (int kc = 0; kc < 4; ++kc)
                c0 = __builtin_amdgcn_mfma_f32_32x32x16_f16(A1[kc], Bh0[kc], c0, 0, 0, 0);
#pragma unroll
            for (int kc = 0; kc < 4; ++kc)
                c1 = __builtin_amdgcn_mfma_f32_32x32x16_f16(A1[kc], Bh1[kc], c1, 0, 0, 0);
            const int col = half * 16 + ((t0 + 1) & 15);
            {
                float q0 = min3f(c0[0], c0[1], c0[2]);
                float q1 = min3f(c0[3], c0[4], c0[5]);
                float q2 = min3f(c0[6], c0[7], c0[8]);
                float q3 = min3f(c0[9], c0[10], c0[11]);
                float q4 = min3f(c0[12], c0[13], c0[14]);
                stage[wave][l31][col] = fminf(min3f(q0, q1, q2), min3f(q3, q4, c0[15]));
            }
            {
                float q0 = min3f(c1[0], c1[1], c1[2]);
                float q1 = min3f(c1[3], c1[4], c1[5]);
                float q2 = min3f(c1[6], c1[7], c1[8]);
                float q3 = min3f(c1[9], c1[10], c1[11]);
                float q4 = min3f(c1[12], c1[13], c1[14]);
                stage[wave][32 + l31][col] = fminf(min3f(q0, q1, q2), min3f(q3, q4, c1[15]));
            }
        }
        if ((t0 & 15) == 14) {  // tiles [fph*16, fph*16+16) done -> flush fp16
            const int fph = t0 >> 4;                     // 0 or 1
            unsigned short* dst0 = minbuf16 + (size_t)blockIdx.y * 64 + fph * 32;
#pragma unroll
            for (int it = 0; it < 4; ++it) {
                int idx = it * 64 + lane;                // 0..255
                int r = idx >> 2;                        // 0..63
                int p = idx & 3;                         // 16B piece (8 fp16)
                const float* s = &stage[wave][r][p * 8];
                unsigned w[8];
#pragma unroll
                for (int e = 0; e < 8; ++e)
                    w[e] = (unsigned)__builtin_bit_cast(unsigned short, (_Float16)s[e]);
                *reinterpret_cast<uint4*>(dst0 + (size_t)(i0 + r) * 512 + p * 8) = pack8(w);
            }
        }
    }
}

// ---------------- K3: wave-per-row, bitonic theta + two-stage rescan ---------
__global__ __launch_bounds__(256) void ksel_kernel(const float* __restrict__ xnT,
                                                   const float* __restrict__ sq,
                                                   const unsigned short* __restrict__ minbuf16,
                                                   const unsigned short* __restrict__ Phi,
                                                   int* __restrict__ out) {
    __shared__ unsigned short glist[4][40];
    __shared__ unsigned short jlist[4][64];
    const int lane = threadIdx.x & 63;
    const int wave = threadIdx.x >> 6;
    const int t = blockIdx.x * 4 + wave;                 // row id
    const int tu = __builtin_amdgcn_readfirstlane(t);    // wave-uniform row
    const int b = tu >> 13;
    const int n = tu & (NN - 1);

    // lane's 8 group-mins (fp16, one dwordx4; 1KB contiguous per wave)
    float gm[8];
    {
        uint4 a = *reinterpret_cast<const uint4*>(minbuf16 + (size_t)tu * 512 + lane * 8);
        unsigned wv[4] = {a.x, a.y, a.z, a.w};
#pragma unroll
        for (int q4 = 0; q4 < 4; ++q4) {
            gm[q4 * 2 + 0] = (float)__builtin_bit_cast(_Float16, (unsigned short)(wv[q4] & 0xFFFFu));
            gm[q4 * 2 + 1] = (float)__builtin_bit_cast(_Float16, (unsigned short)(wv[q4] >> 16));
        }
    }

    // th9p: bitonic-sort the 64 lane-mins (ascending); lane 8 holds 9th-smallest
    float sv = fminf(min3f(gm[0], gm[1], gm[2]),
                     fminf(min3f(gm[3], gm[4], gm[5]), fminf(gm[6], gm[7])));
#pragma unroll
    for (int k = 2; k <= 64; k <<= 1) {
#pragma unroll
        for (int jj = k >> 1; jj >= 1; jj >>= 1) {
            float o = __shfl_xor(sv, jj);
            bool keepMin = (((lane & jj) == 0) == ((lane & k) == 0));
            sv = keepMin ? fminf(sv, o) : fmaxf(sv, o);
        }
    }
    const float th9p = __shfl(sv, 8);
    const float theta  = th9p + 8e-3f;     // group window (fp16-quant bound, R10)
    const float kappa1 = th9p + 7.5e-3f;   // stage-1 cutoff (fp16 dot + quant, R10)

    // ballot-compact candidate groups (storage indices) into LDS list
    int cnt = 0;
    unsigned short* gl = &glist[wave][0];
#pragma unroll
    for (int q = 0; q < 8; ++q) {
        bool c = gm[q] <= theta;
        unsigned long long mask = __ballot(c);
        int pos = cnt + __popcll(mask & ((1ULL << lane) - 1ULL));
        if (c && pos < 40) gl[pos] = (unsigned short)(lane * 8 + q);
        cnt += (int)__popcll(mask);
    }
    __syncthreads();

    // fp16 row for stage-1 (wave-uniform address -> scalar loads)
    const unsigned short* __restrict__ Pb = Phi + ((size_t)b * NN) * DD;
    H2x4 arh[8];
    {
        const f16x8* pr = reinterpret_cast<const f16x8*>(Phi + (size_t)tu * DD);
#pragma unroll
        for (int c8 = 0; c8 < 8; ++c8) arh[c8] = __builtin_bit_cast(H2x4, pr[c8]);
    }

    // ---- stage 1: fp16-row gather (L2-resident) + v_dot2 filter -------------
    const bool ovf = (cnt > 40);
    const int total = ovf ? NN : cnt * 16;
    const int nIt = (total + 63) >> 6;
    int S1 = 0;
    unsigned short* jl = &jlist[wave][0];
#pragma unroll 1
    for (int m = 0; m < nIt; ++m) {
        const int idx = m * 64 + lane;
        const bool act = idx < total;
        float m2ap = __uint_as_float(0x7f800000u);
        int j = 0;
        if (act) {
            j = ovf ? idx : s_to_j((int)gl[idx >> 4], idx & 15);
            const f16x8* p8 = reinterpret_cast<const f16x8*>(Pb + (size_t)j * DD);
            float a0 = 0.0f, a1 = 0.0f, a2 = 0.0f, a3 = 0.0f;
#pragma unroll
            for (int c8 = 0; c8 < 8; ++c8) {
                H2x4 g2 = __builtin_bit_cast(H2x4, p8[c8]);
                a0 = dot2acc(g2.a, arh[c8].a, a0);
                a1 = dot2acc(g2.b, arh[c8].b, a1);
                a2 = dot2acc(g2.c, arh[c8].c, a2);
                a3 = dot2acc(g2.d, arh[c8].d, a3);
            }
            m2ap = -2.0f * ((a0 + a1) + (a2 + a3));
        }
        bool pass = act && (m2ap <= kappa1);
        unsigned long long mask = __ballot(pass);
        int pos = S1 + __popcll(mask & ((1ULL << lane) - 1ULL));
        if (pass && pos < 64) jl[pos] = (unsigned short)j;
        S1 += (int)__popcll(mask);
    }
    __syncthreads();

    // exact fp32 row (loaded after stage-1 so arh SGPRs can retire)
    const float* __restrict__ Bb = xnT + (size_t)b * NN * DD;
    const float* __restrict__ sqb = sq + (size_t)b * NN;
    float ar[DD];
    {
        const float4* a4 = reinterpret_cast<const float4*>(xnT + (size_t)tu * DD);
#pragma unroll
        for (int d = 0; d < DD; d += 4) {
            float4 f = a4[d >> 2];
            ar[d] = f.x; ar[d + 1] = f.y; ar[d + 2] = f.z; ar[d + 3] = f.w;
        }
    }

    unsigned long long kout = ~0ULL;
    if (S1 <= 64) {
        // ---- stage 2: exact fp32 keys for survivors + ONE u64 bitonic -------
        unsigned long long v = ~0ULL;
        if (lane < S1) {
            int j = (int)jl[lane];
            const float4* bc4 = reinterpret_cast<const float4*>(Bb + (size_t)j * DD);
            float a0 = 0.0f, a1 = 0.0f, a2 = 0.0f, a3 = 0.0f;
#pragma unroll
            for (int d4 = 0; d4 < DD / 4; ++d4) {
                float4 f = bc4[d4];
                a0 = fmaf(ar[4 * d4 + 0], f.x, a0);
                a1 = fmaf(ar[4 * d4 + 1], f.y, a1);
                a2 = fmaf(ar[4 * d4 + 2], f.z, a2);
                a3 = fmaf(ar[4 * d4 + 3], f.w, a3);
            }
            float dot = (a0 + a1) + (a2 + a3);
            float key = fmaf(-2.0f, dot, sqb[j]);        // byte-identical ordering key
            unsigned ub = __float_as_uint(key);
            ub ^= (0x80000000u | (unsigned)((int)ub >> 31));
            v = ((unsigned long long)ub << 32) | (unsigned)j;
        }
#pragma unroll
        for (int k = 2; k <= 64; k <<= 1) {
#pragma unroll
            for (int jj = k >> 1; jj >= 1; jj >>= 1) {
                unsigned long long o = __shfl_xor(v, jj);
                bool keepMin = (((lane & jj) == 0) == ((lane & k) == 0));
                bool less = o < v;
                unsigned long long mn = less ? o : v;
                unsigned long long mx = less ? v : o;
                v = keepMin ? mn : mx;
            }
        }
        kout = v;
    } else {
        // rare: exact per-lane kd[9] + 9-round butterfly over the candidate set
        unsigned long long kd[KK];
#pragma unroll
        for (int m = 0; m < KK; ++m) kd[m] = ~0ULL;
#pragma unroll 1
        for (int m = 0; m < nIt; ++m) {
            const int idx = m * 64 + lane;
            if (idx >= total) continue;
            int j = ovf ? idx : s_to_j((int)gl[idx >> 4], idx & 15);
            const float4* bc4 = reinterpret_cast<const float4*>(Bb + (size_t)j * DD);
            float a0 = 0.0f, a1 = 0.0f, a2 = 0.0f, a3 = 0.0f;
#pragma unroll
            for (int d4 = 0; d4 < DD / 4; ++d4) {
                float4 f = bc4[d4];
                a0 = fmaf(ar[4 * d4 + 0], f.x, a0);
                a1 = fmaf(ar[4 * d4 + 1], f.y, a1);
                a2 = fmaf(ar[4 * d4 + 2], f.z, a2);
                a3 = fmaf(ar[4 * d4 + 3], f.w, a3);
            }
            float dot = (a0 + a1) + (a2 + a3);
            float key = fmaf(-2.0f, dot, sqb[j]);
            unsigned ub = __float_as_uint(key);
            ub ^= (0x80000000u | (unsigned)((int)ub >> 31));
            unsigned long long cnd = ((unsigned long long)ub << 32) | (unsigned)j;
            if (cnd < kd[KK - 1]) {
#pragma unroll
                for (int m2 = 0; m2 < KK; ++m2) {
                    bool sw = cnd < kd[m2];
                    unsigned long long lo = sw ? cnd : kd[m2];
                    unsigned long long hi = sw ? kd[m2] : cnd;
                    kd[m2] = lo;
                    cnd = hi;
                }
            }
        }
#pragma unroll
        for (int r = 0; r < KK; ++r) {
            unsigned long long c = kd[0];
            unsigned long long wm = c;
#pragma unroll
            for (int d = 1; d < 64; d <<= 1) {
                unsigned long long o = __shfl_xor(wm, d);
                wm = (o < wm) ? o : wm;
            }
            if (lane == r) kout = wm;
            if (c == wm) {
#pragma unroll
                for (int m2 = 0; m2 < KK - 1; ++m2) kd[m2] = kd[m2 + 1];
                kd[KK - 1] = ~0ULL;
            }
        }
    }

    if (lane < KK) {
        out[(size_t)tu * KK + lane] = (int)(kout & 0xFFFFFFFFULL);
        out[(size_t)BB * NN * KK + (size_t)tu * KK + lane] = n;
    }
}

// ===========================================================================
// OLD PATH (verified fallback) -- unchanged
// ===========================================================================
__global__ __launch_bounds__(256) void knorm_kernel(const float* __restrict__ x,
                                                    float* __restrict__ xnT,
                                                    float* __restrict__ sq) {
    int t = blockIdx.x * 256 + threadIdx.x;
    int b = t >> 13;
    int n = t & (NN - 1);
    const float* xb = x + (size_t)b * DD * NN + n;
    float v[DD];
    float ss = 0.0f;
#pragma unroll
    for (int d = 0; d < DD; ++d) {
        v[d] = xb[(size_t)d * NN];
        ss = fmaf(v[d], v[d], ss);
    }
    float norm = sqrtf(ss);
    float inv = 1.0f / fmaxf(norm, 1e-12f);
    float s2 = 0.0f;
#pragma unroll
    for (int d = 0; d < DD; ++d) {
        float xv = v[d] * inv;
        v[d] = xv;
        s2 = fmaf(xv, xv, s2);
    }
    float4* o4 = reinterpret_cast<float4*>(xnT + (size_t)t * DD);
#pragma unroll
    for (int d = 0; d < DD; d += 4) {
        o4[d >> 2] = make_float4(v[d], v[d + 1], v[d + 2], v[d + 3]);
    }
    sq[t] = s2;
}

template <int S>
__global__ __launch_bounds__(256, 2) void kdist_kernel(const float* __restrict__ xnT,
                                                       const float* __restrict__ sq,
                                                       unsigned long long* __restrict__ cand) {
    const int rb = blockIdx.x;
    const int b = rb >> 5;
    const int nbase = (rb & 31) * 256;
    const int n = nbase + threadIdx.x;
    const int s = blockIdx.y;
    const int jcount = NN / S;
    const int j0 = s * jcount;
    const int j1 = j0 + jcount;

    const float* __restrict__ Bb = xnT + ((size_t)b * NN) * DD;
    const float* __restrict__ sqb = sq + (size_t)b * NN;

    float ar[DD];
    {
        const float4* a4 = reinterpret_cast<const float4*>(Bb + (size_t)n * DD);
#pragma unroll
        for (int d = 0; d < DD; d += 4) {
            float4 f = a4[d >> 2];
            ar[d] = f.x; ar[d + 1] = f.y; ar[d + 2] = f.z; ar[d + 3] = f.w;
        }
    }
#pragma unroll
    for (int d = 0; d < DD; ++d) {
        asm volatile("" : "+v"(ar[d]));
    }

    unsigned long long kd[KK];
#pragma unroll
    for (int m = 0; m < KK; ++m) kd[m] = ~0ULL;

#pragma unroll 2
    for (int j = j0; j < j1; ++j) {
        const float4* bc4 = reinterpret_cast<const float4*>(Bb + (size_t)j * DD);
        float a0 = 0.0f, a1 = 0.0f, a2 = 0.0f, a3 = 0.0f;
#pragma unroll
        for (int d4 = 0; d4 < DD / 4; ++d4) {
            float4 f = bc4[d4];
            a0 = fmaf(ar[4 * d4 + 0], f.x, a0);
            a1 = fmaf(ar[4 * d4 + 1], f.y, a1);
            a2 = fmaf(ar[4 * d4 + 2], f.z, a2);
            a3 = fmaf(ar[4 * d4 + 3], f.w, a3);
        }
        float dot = (a0 + a1) + (a2 + a3);
        float key = fmaf(-2.0f, dot, sqb[j]);
        unsigned int ub = __float_as_uint(key);
        ub ^= (0x80000000u | (unsigned int)((int)ub >> 31));
        unsigned long long cnd = ((unsigned long long)ub << 32) | (unsigned int)j;
        if (cnd < kd[KK - 1]) {
#pragma unroll
            for (int m = 0; m < KK; ++m) {
                bool sw = cnd < kd[m];
                unsigned long long lo = sw ? cnd : kd[m];
                unsigned long long hi = sw ? kd[m] : cnd;
                kd[m] = lo;
                cnd = hi;
            }
        }
    }

    unsigned long long* outc = cand + ((size_t)(b * NN + n) * S + s) * KK;
#pragma unroll
    for (int m = 0; m < KK; ++m) outc[m] = kd[m];
}

template <int S>
__global__ __launch_bounds__(256) void kmerge_kernel(const unsigned long long* __restrict__ cand,
                                                     int* __restrict__ out) {
    int t = blockIdx.x * 256 + threadIdx.x;
    const unsigned long long* c = cand + (size_t)t * (S * KK);
    unsigned long long kd[KK];
#pragma unroll
    for (int m = 0; m < KK; ++m) kd[m] = ~0ULL;
#pragma unroll
    for (int q = 0; q < S * KK; ++q) {
        unsigned long long cnd = c[q];
        if (cnd < kd[KK - 1]) {
#pragma unroll
            for (int m = 0; m < KK; ++m) {
                bool sw = cnd < kd[m];
                unsigned long long lo = sw ? cnd : kd[m];
                unsigned long long hi = sw ? kd[m] : cnd;
                kd[m] = lo;
                cnd = hi;
            }
        }
    }
    int n = t & (NN - 1);
    int* out0 = out + (size_t)t * KK;
    int* out1 = out + (size_t)BB * NN * KK + (size_t)t * KK;
#pragma unroll
    for (int m = 0; m < KK; ++m) {
        out0[m] = (int)(kd[m] & 0xFFFFFFFFULL);
        out1[m] = n;
    }
}

extern "C" void kernel_launch(void* const* d_in, const int* in_sizes, int n_in,
                              void* d_out, int out_size, void* d_ws, size_t ws_size,
                              hipStream_t stream) {
    const float* x = (const float*)d_in[0];
    int* out = (int*)d_out;
    char* ws = (char*)d_ws;

    // Shared layout head
    constexpr size_t XNT_B = (size_t)BB * NN * DD * 4;          //  8,388,608
    constexpr size_t SQ_B  = (size_t)BB * NN * 4;               //    131,072
    float* xnT = (float*)ws;
    float* sq  = (float*)(ws + XNT_B);

    // New-path layout (offsets kept from the verified R2 layout; Plo/Slo slots
    // unused but reserved so NEED_NEW is unchanged; minbuf now fp16 = 32MB of
    // the 64MB reserved region)
    constexpr size_t BF_B  = (size_t)BB * NN * DD * 2;          //  4,194,304 each
    constexpr size_t OFF_PHI = XNT_B + SQ_B;
    constexpr size_t OFF_PLO = OFF_PHI + BF_B;
    constexpr size_t OFF_SHI = OFF_PLO + BF_B;
    constexpr size_t OFF_SLO = OFF_SHI + BF_B;
    constexpr size_t OFF_MIN = OFF_SLO + BF_B;
    constexpr size_t MIN_B   = (size_t)512 * BB * NN * 4;       // 67,108,864 (reserved)
    constexpr size_t NEED_NEW = OFF_MIN + MIN_B;                // 92,405,760

    if (ws_size >= NEED_NEW) {
        unsigned short* Phi = (unsigned short*)(ws + OFF_PHI);
        unsigned short* Shi = (unsigned short*)(ws + OFF_SHI);
        unsigned short* minbuf16 = (unsigned short*)(ws + OFF_MIN);

        knorm2_kernel<<<dim3(BB * NN / 256), dim3(256), 0, stream>>>(x, xnT, sq, Phi, Shi);
        kmin_kernel<<<dim3(BB * NN / 256, 8), dim3(256), 0, stream>>>(Shi, Phi, minbuf16);
        ksel_kernel<<<dim3(BB * NN / 4), dim3(256), 0, stream>>>(xnT, sq, minbuf16, Phi, out);
        return;
    }

    // Old verified path
    unsigned long long* cand = (unsigned long long*)(ws + XNT_B + SQ_B);
    const size_t base = XNT_B + SQ_B;
    const size_t need8 = base + (size_t)BB * NN * 8 * KK * 8;

    knorm_kernel<<<dim3(BB * NN / 256), dim3(256), 0, stream>>>(x, xnT, sq);
    if (ws_size >= need8) {
        kdist_kernel<8><<<dim3(BB * NN / 256, 8), dim3(256), 0, stream>>>(xnT, sq, cand);
        kmerge_kernel<8><<<dim3(BB * NN / 256), dim3(256), 0, stream>>>(cand, out);
    } else {
        kdist_kernel<4><<<dim3(BB * NN / 256, 4), dim3(256), 0, stream>>>(xnT, sq, cand);
        kmerge_kernel<4><<<dim3(BB * NN / 256), dim3(256), 0, stream>>>(cand, out);
    }
}

// Round 11
// 243.228 us; speedup vs baseline: 1.5779x; 1.0097x over previous
//
#include <hip/hip_runtime.h>

// Problem constants (fixed by setup_inputs): x (4, 64, 8192, 1) fp32, k=9, dilation=1
#define BB 4
#define DD 64
#define NN 8192
#define KK 9

// ---------------------------------------------------------------------------
// MFMA filter + exact rescan
//   K1 knorm2: normalize, emit fp32 xnT, sq, fp16 casts P=fp16(xn), S=fp16(-2xn)
//   K2 kmin:   fp16 MFMA GEMM -> per-(row, 16-j-group) min of approx -2*dot.
//              fp16 minbuf (R10), s = jsplit*64 + fph*32 + half*16 + u,
//              one full 64B line per row per flush. UNCHANGED from R10.
//   K3 ksel:   R11: TWO independent rows per wave (tA, tB = tA+1, both
//              readfirstlane-uniform -> rows stay scalar/SGPR, avoiding R7's
//              VGPR blowup). R9/R10 post-mortems: ksel is per-wave serial-
//              latency bound (~36K cy/wave: gm HBM load, shfl bitonics,
//              dependent gather rounds); pairing overlaps two independent
//              chains per phase -> wave count halves at ~1.3x per-wave cost.
//              Also removed both __syncthreads: glist/jlist are WAVE-PRIVATE
//              ([wave]-indexed); within-wave LDS ordering is program-order —
//              the block barrier only coupled the 4 waves' latency chains.
//       Per-row logic and thresholds UNCHANGED (R10-verified):
//       th9p' bitonic; theta = th9p'+8e-3; kappa1 = th9p'+7.5e-3 (fp16 dot);
//       stage-2 exact fp32 keys + u64 bitonic (byte-identical tie-break);
//       fallbacks: cnt>40 -> full scan; S1>64 -> exact per-lane kd[9].
// Fallback to the original verified path if ws_size is too small.
// ---------------------------------------------------------------------------

typedef __attribute__((ext_vector_type(8))) _Float16 f16x8;  // 4 VGPR MFMA operand
typedef __attribute__((ext_vector_type(16))) float f32x16;   // 32x32 accumulator
typedef __attribute__((ext_vector_type(2))) _Float16 h2;     // v_dot2 operand
struct H2x4 { h2 a, b, c, d; };

__device__ __forceinline__ uint4 pack8(const unsigned* w) {
    return make_uint4(w[0] | (w[1] << 16), w[2] | (w[3] << 16),
                      w[4] | (w[5] << 16), w[6] | (w[7] << 16));
}

__device__ __forceinline__ float min3f(float a, float b, float c) {
    return fminf(fminf(a, b), c);            // clang fuses to v_min3_f32
}

__device__ __forceinline__ float dot2acc(h2 g, h2 r, float acc) {
#if __has_builtin(__builtin_amdgcn_fdot2)
    return __builtin_amdgcn_fdot2(g, r, acc, false);
#else
    acc = fmaf((float)g[0], (float)r[0], acc);
    return fmaf((float)g[1], (float)r[1], acc);
#endif
}

// storage-index -> j mapping: s = jsplit*64 + fph*32 + half*16 + u
// tile T = jsplit*32 + fph*16 + u ; j = T*32 + (s4>>2)*8 + half*4 + (s4&3)
__device__ __forceinline__ int s_to_j(int g, int s4) {
    int T = ((g >> 6) << 5) + (((g >> 5) & 1) << 4) + (g & 15);
    return T * 32 + ((s4 >> 2) << 3) + (((g >> 4) & 1) << 2) + (s4 & 3);
}

// ---------------- K1: normalize + fp32 pack + sq + fp16 casts -----------------
__global__ __launch_bounds__(256) void knorm2_kernel(const float* __restrict__ x,
                                                     float* __restrict__ xnT,
                                                     float* __restrict__ sq,
                                                     unsigned short* __restrict__ Phi,
                                                     unsigned short* __restrict__ Shi) {
    int t = blockIdx.x * 256 + threadIdx.x;      // row id 0..B*N-1
    int b = t >> 13;
    int n = t & (NN - 1);
    const float* xb = x + (size_t)b * DD * NN + n;
    float v[DD];
    float ss = 0.0f;
#pragma unroll
    for (int d = 0; d < DD; ++d) {
        v[d] = xb[(size_t)d * NN];
        ss = fmaf(v[d], v[d], ss);
    }
    float inv = 1.0f / fmaxf(sqrtf(ss), 1e-12f);
    float s2 = 0.0f;
#pragma unroll
    for (int d = 0; d < DD; ++d) {
        v[d] *= inv;
        s2 = fmaf(v[d], v[d], s2);
    }
    sq[t] = s2;
    float4* o4 = reinterpret_cast<float4*>(xnT + (size_t)t * DD);
#pragma unroll
    for (int d = 0; d < DD; d += 4) o4[d >> 2] = make_float4(v[d], v[d+1], v[d+2], v[d+3]);

    size_t base = (size_t)t * DD;
#pragma unroll
    for (int d0 = 0; d0 < DD; d0 += 8) {
        unsigned ph[8], sh[8];
#pragma unroll
        for (int e = 0; e < 8; ++e) {
            float f = v[d0 + e];
            _Float16 hp = (_Float16)f;               // v_cvt_f16_f32 (RNE)
            _Float16 hs = (_Float16)(-2.0f * f);     // exact scale before rounding
            ph[e] = (unsigned)__builtin_bit_cast(unsigned short, hp);
            sh[e] = (unsigned)__builtin_bit_cast(unsigned short, hs);
        }
        *reinterpret_cast<uint4*>(Phi + base + d0) = pack8(ph);
        *reinterpret_cast<uint4*>(Shi + base + d0) = pack8(sh);
    }
}

// ---------------- K2: MFMA min pass (fp16, 64 rows/wave, fp16 minbuf) --------
// UNCHANGED from R10 (two consecutive nulls on blind kmin opts; waiting for
// counters — R11's faster ksel will surface kmin in the top-5).
__global__ __launch_bounds__(256, 4) void kmin_kernel(const unsigned short* __restrict__ Shi,
                                                      const unsigned short* __restrict__ Phi,
                                                      unsigned short* __restrict__ minbuf16) {
    __shared__ float stage[4][64][33];                  // 33.8 KB/block
    const int lane = threadIdx.x & 63;
    const int wave = threadIdx.x >> 6;
    const int l31 = lane & 31;
    const int half = lane >> 5;
    const int i0 = blockIdx.x * 256 + wave * 64;        // global i-row base
    const int b = i0 >> 13;                             // 256 | 8192 -> uniform
    const int jloc0 = blockIdx.y * (NN / 8);            // batch-local j start

    f16x8 Bh0[4], Bh1[4];
    {
        const size_t ib0 = (size_t)(i0 + l31) * DD + half * 8;
        const size_t ib1 = (size_t)(i0 + 32 + l31) * DD + half * 8;
#pragma unroll
        for (int kc = 0; kc < 4; ++kc) {
            Bh0[kc] = *reinterpret_cast<const f16x8*>(Phi + ib0 + kc * 16);
            Bh1[kc] = *reinterpret_cast<const f16x8*>(Phi + ib1 + kc * 16);
        }
    }
    const size_t ja0 = ((size_t)b * NN + jloc0 + l31) * DD + half * 8;

    f16x8 A0[4], A1[4];
#pragma unroll
    for (int kc = 0; kc < 4; ++kc)
        A0[kc] = *reinterpret_cast<const f16x8*>(Shi + ja0 + kc * 16);

#pragma unroll 2
    for (int u2 = 0; u2 < 16; ++u2) {
        const int t0 = u2 * 2;                          // even tile
        {   // prefetch odd tile
            const size_t ja = ja0 + (size_t)(t0 + 1) * 32 * DD;
#pragma unroll
            for (int kc = 0; kc < 4; ++kc)
                A1[kc] = *reinterpret_cast<const f16x8*>(Shi + ja + kc * 16);
        }
        {   // consume even tile (A0)
            f32x16 c0 = {}, c1 = {};
#pragma unroll
            for (int kc = 0; kc < 4; ++kc)
                c0 = __builtin_amdgcn_mfma_f32_32x32x16_f16(A0[kc], Bh0[kc], c0, 0, 0, 0);
#pragma unroll
            for (int kc = 0; kc < 4; ++kc)
                c1 = __builtin_amdgcn_mfma_f32_32x32x16_f16(A0[kc], Bh1[kc], c1, 0, 0, 0);
            const int col = half * 16 + (t0 & 15);
            {
                float q0 = min3f(c0[0], c0[1], c0[2]);
                float q1 = min3f(c0[3], c0[4], c0[5]);
                float q2 = min3f(c0[6], c0[7], c0[8]);
                float q3 = min3f(c0[9], c0[10], c0[11]);
                float q4 = min3f(c0[12], c0[13], c0[14]);
                stage[wave][l31][col] = fminf(min3f(q0, q1, q2), min3f(q3, q4, c0[15]));
            }
            {
                float q0 = min3f(c1[0], c1[1], c1[2]);
                float q1 = min3f(c1[3], c1[4], c1[5]);
                float q2 = min3f(c1[6], c1[7], c1[8]);
                float q3 = min3f(c1[9], c1[10], c1[11]);
                float q4 = min3f(c1[12], c1[13], c1[14]);
                stage[wave][32 + l31][col] = fminf(min3f(q0, q1, q2), min3f(q3, q4, c1[15]));
            }
        }
        if (u2 < 15) {  // prefetch next even tile
            const size_t ja = ja0 + (size_t)(t0 + 2) * 32 * DD;
#pragma unroll
            for (int kc = 0; kc < 4; ++kc)
                A0[kc] = *reinterpret_cast<const f16x8*>(Shi + ja + kc * 16);
        }
        {   // consume odd tile (A1)
            f32x16 c0 = {}, c1 = {};
#pragma unroll
            for (int kc = 0; kc < 4; ++kc)
                c0 = __builtin_amdgcn_mfma_f32_32x32x16_f16(A1[kc], Bh0[kc], c0, 0, 0, 0);
#pragma unroll
            for (int kc = 0; kc < 4; ++kc)
                c1 = __builtin_amdgcn_mfma_f32_32x32x16_f16(A1[kc], Bh1[kc], c1, 0, 0, 0);
            const int col = half * 16 + ((t0 + 1) & 15);
            {
                float q0 = min3f(c0[0], c0[1], c0[2]);
                float q1 = min3f(c0[3], c0[4], c0[5]);
                float q2 = min3f(c0[6], c0[7], c0[8]);
                float q3 = min3f(c0[9], c0[10], c0[11]);
                float q4 = min3f(c0[12], c0[13], c0[14]);
                stage[wave][l31][col] = fminf(min3f(q0, q1, q2), min3f(q3, q4, c0[15]));
            }
            {
                float q0 = min3f(c1[0], c1[1], c1[2]);
                float q1 = min3f(c1[3], c1[4], c1[5]);
                float q2 = min3f(c1[6], c1[7], c1[8]);
                float q3 = min3f(c1[9], c1[10], c1[11]);
                float q4 = min3f(c1[12], c1[13], c1[14]);
                stage[wave][32 + l31][col] = fminf(min3f(q0, q1, q2), min3f(q3, q4, c1[15]));
            }
        }
        if ((t0 & 15) == 14) {  // tiles [fph*16, fph*16+16) done -> flush fp16
            const int fph = t0 >> 4;                     // 0 or 1
            unsigned short* dst0 = minbuf16 + (size_t)blockIdx.y * 64 + fph * 32;
#pragma unroll
            for (int it = 0; it < 4; ++it) {
                int idx = it * 64 + lane;                // 0..255
                int r = idx >> 2;                        // 0..63
                int p = idx & 3;                         // 16B piece (8 fp16)
                const float* s = &stage[wave][r][p * 8];
                unsigned w[8];
#pragma unroll
                for (int e = 0; e < 8; ++e)
                    w[e] = (unsigned)__builtin_bit_cast(unsigned short, (_Float16)s[e]);
                *reinterpret_cast<uint4*>(dst0 + (size_t)(i0 + r) * 512 + p * 8) = pack8(w);
            }
        }
    }
}

// ---------------- K3: 2 rows per wave, interleaved chains --------------------
__global__ __launch_bounds__(256) void ksel_kernel(const float* __restrict__ xnT,
                                                   const float* __restrict__ sq,
                                                   const unsigned short* __restrict__ minbuf16,
                                                   const unsigned short* __restrict__ Phi,
                                                   int* __restrict__ out) {
    __shared__ unsigned short glist[4][2][40];           // wave-private
    __shared__ unsigned short jlist[4][2][64];           // wave-private
    const int lane = threadIdx.x & 63;
    const int wave = threadIdx.x >> 6;
    const int tA = __builtin_amdgcn_readfirstlane(blockIdx.x * 8 + wave * 2);
    const int tB = tA + 1;
    const int b = tA >> 13;                              // pair shares batch (8|8192)
    const int nA = tA & (NN - 1);
    const int nB = tB & (NN - 1);

    // both rows' 8 group-mins (two independent loads in flight)
    float gmA[8], gmB[8];
    {
        uint4 a = *reinterpret_cast<const uint4*>(minbuf16 + (size_t)tA * 512 + lane * 8);
        uint4 c = *reinterpret_cast<const uint4*>(minbuf16 + (size_t)tB * 512 + lane * 8);
        unsigned wa[4] = {a.x, a.y, a.z, a.w};
        unsigned wb[4] = {c.x, c.y, c.z, c.w};
#pragma unroll
        for (int q4 = 0; q4 < 4; ++q4) {
            gmA[q4*2+0] = (float)__builtin_bit_cast(_Float16, (unsigned short)(wa[q4] & 0xFFFFu));
            gmA[q4*2+1] = (float)__builtin_bit_cast(_Float16, (unsigned short)(wa[q4] >> 16));
            gmB[q4*2+0] = (float)__builtin_bit_cast(_Float16, (unsigned short)(wb[q4] & 0xFFFFu));
            gmB[q4*2+1] = (float)__builtin_bit_cast(_Float16, (unsigned short)(wb[q4] >> 16));
        }
    }

    // interleaved 21-stage bitonics (two independent shfl chains pipeline)
    float svA = fminf(min3f(gmA[0], gmA[1], gmA[2]),
                      fminf(min3f(gmA[3], gmA[4], gmA[5]), fminf(gmA[6], gmA[7])));
    float svB = fminf(min3f(gmB[0], gmB[1], gmB[2]),
                      fminf(min3f(gmB[3], gmB[4], gmB[5]), fminf(gmB[6], gmB[7])));
#pragma unroll
    for (int k = 2; k <= 64; k <<= 1) {
#pragma unroll
        for (int jj = k >> 1; jj >= 1; jj >>= 1) {
            float oA = __shfl_xor(svA, jj);
            float oB = __shfl_xor(svB, jj);
            bool keepMin = (((lane & jj) == 0) == ((lane & k) == 0));
            svA = keepMin ? fminf(svA, oA) : fmaxf(svA, oA);
            svB = keepMin ? fminf(svB, oB) : fmaxf(svB, oB);
        }
    }
    const float th9pA = __shfl(svA, 8);
    const float th9pB = __shfl(svB, 8);
    const float thetaA  = th9pA + 8e-3f,  thetaB  = th9pB + 8e-3f;
    const float kappa1A = th9pA + 7.5e-3f, kappa1B = th9pB + 7.5e-3f;

    // ballot-compact candidate groups for both rows (wave-private LDS)
    int cntA = 0, cntB = 0;
    unsigned short* glA = &glist[wave][0][0];
    unsigned short* glB = &glist[wave][1][0];
#pragma unroll
    for (int q = 0; q < 8; ++q) {
        bool cA = gmA[q] <= thetaA;
        unsigned long long mA = __ballot(cA);
        int pA = cntA + __popcll(mA & ((1ULL << lane) - 1ULL));
        if (cA && pA < 40) glA[pA] = (unsigned short)(lane * 8 + q);
        cntA += (int)__popcll(mA);
        bool cB = gmB[q] <= thetaB;
        unsigned long long mB = __ballot(cB);
        int pB = cntB + __popcll(mB & ((1ULL << lane) - 1ULL));
        if (cB && pB < 40) glB[pB] = (unsigned short)(lane * 8 + q);
        cntB += (int)__popcll(mB);
    }
    // no __syncthreads: lists are wave-private; within-wave LDS ordering is
    // program-order (the old block barrier only coupled the 4 waves).

    // fp16 rows (wave-uniform -> scalar/SGPR)
    const unsigned short* __restrict__ Pb = Phi + ((size_t)b * NN) * DD;
    H2x4 arhA[8], arhB[8];
    {
        const f16x8* prA = reinterpret_cast<const f16x8*>(Phi + (size_t)tA * DD);
        const f16x8* prB = reinterpret_cast<const f16x8*>(Phi + (size_t)tB * DD);
#pragma unroll
        for (int c8 = 0; c8 < 8; ++c8) {
            arhA[c8] = __builtin_bit_cast(H2x4, prA[c8]);
            arhB[c8] = __builtin_bit_cast(H2x4, prB[c8]);
        }
    }

    // ---- stage 1: fused gather+filter for both rows -------------------------
    const bool ovfA = (cntA > 40), ovfB = (cntB > 40);
    const int totalA = ovfA ? NN : cntA * 16;
    const int totalB = ovfB ? NN : cntB * 16;
    const int nItA = (totalA + 63) >> 6, nItB = (totalB + 63) >> 6;
    const int nIt = nItA > nItB ? nItA : nItB;
    int S1A = 0, S1B = 0;
    unsigned short* jlA = &jlist[wave][0][0];
    unsigned short* jlB = &jlist[wave][1][0];
#pragma unroll 1
    for (int m = 0; m < nIt; ++m) {
        const int idx = m * 64 + lane;
        const bool actA = idx < totalA;
        const bool actB = idx < totalB;
        float m2A = __uint_as_float(0x7f800000u);
        float m2B = __uint_as_float(0x7f800000u);
        int jA = 0, jB = 0;
        if (actA) {
            jA = ovfA ? idx : s_to_j((int)glA[idx >> 4], idx & 15);
            const f16x8* p8 = reinterpret_cast<const f16x8*>(Pb + (size_t)jA * DD);
            float a0 = 0.0f, a1 = 0.0f, a2 = 0.0f, a3 = 0.0f;
#pragma unroll
            for (int c8 = 0; c8 < 8; ++c8) {
                H2x4 g2 = __builtin_bit_cast(H2x4, p8[c8]);
                a0 = dot2acc(g2.a, arhA[c8].a, a0);
                a1 = dot2acc(g2.b, arhA[c8].b, a1);
                a2 = dot2acc(g2.c, arhA[c8].c, a2);
                a3 = dot2acc(g2.d, arhA[c8].d, a3);
            }
            m2A = -2.0f * ((a0 + a1) + (a2 + a3));
        }
        if (actB) {
            jB = ovfB ? idx : s_to_j((int)glB[idx >> 4], idx & 15);
            const f16x8* p8 = reinterpret_cast<const f16x8*>(Pb + (size_t)jB * DD);
            float a0 = 0.0f, a1 = 0.0f, a2 = 0.0f, a3 = 0.0f;
#pragma unroll
            for (int c8 = 0; c8 < 8; ++c8) {
                H2x4 g2 = __builtin_bit_cast(H2x4, p8[c8]);
                a0 = dot2acc(g2.a, arhB[c8].a, a0);
                a1 = dot2acc(g2.b, arhB[c8].b, a1);
                a2 = dot2acc(g2.c, arhB[c8].c, a2);
                a3 = dot2acc(g2.d, arhB[c8].d, a3);
            }
            m2B = -2.0f * ((a0 + a1) + (a2 + a3));
        }
        bool passA = actA && (m2A <= kappa1A);
        unsigned long long mA = __ballot(passA);
        int pA = S1A + __popcll(mA & ((1ULL << lane) - 1ULL));
        if (passA && pA < 64) jlA[pA] = (unsigned short)jA;
        S1A += (int)__popcll(mA);
        bool passB = actB && (m2B <= kappa1B);
        unsigned long long mB = __ballot(passB);
        int pB = S1B + __popcll(mB & ((1ULL << lane) - 1ULL));
        if (passB && pB < 64) jlB[pB] = (unsigned short)jB;
        S1B += (int)__popcll(mB);
    }

    const float* __restrict__ Bb = xnT + (size_t)b * NN * DD;
    const float* __restrict__ sqb = sq + (size_t)b * NN;

    // ---- stage 2: exact fp32 keys + interleaved u64 bitonics ----------------
    unsigned long long vA = ~0ULL, vB = ~0ULL;
    {
        // issue both survivor gathers first (independent, overlap latency)
        float4 bufA[4], bufB[4];
        int jA = 0, jB = 0;
        const bool hvA = lane < (S1A <= 64 ? S1A : 64);
        const bool hvB = lane < (S1B <= 64 ? S1B : 64);
        if (hvA) {
            jA = (int)jlA[lane];
            const float4* bc4 = reinterpret_cast<const float4*>(Bb + (size_t)jA * DD);
#pragma unroll
            for (int p = 0; p < 4; ++p) bufA[p] = bc4[p * 4];     // [0,4,8,12]
        }
        if (hvB) {
            jB = (int)jlB[lane];
            const float4* bc4 = reinterpret_cast<const float4*>(Bb + (size_t)jB * DD);
#pragma unroll
            for (int p = 0; p < 4; ++p) bufB[p] = bc4[p * 4];
        }
        // row A exact key (ar uniform -> scalar)
        {
            float ar[DD];
            const float4* a4 = reinterpret_cast<const float4*>(xnT + (size_t)tA * DD);
#pragma unroll
            for (int d = 0; d < DD; d += 4) {
                float4 f = a4[d >> 2];
                ar[d] = f.x; ar[d+1] = f.y; ar[d+2] = f.z; ar[d+3] = f.w;
            }
            if (hvA) {
                const float4* bc4 = reinterpret_cast<const float4*>(Bb + (size_t)jA * DD);
                float a0 = 0, a1 = 0, a2 = 0, a3 = 0;
#pragma unroll
                for (int d4 = 0; d4 < 16; ++d4) {
                    float4 f = (d4 % 4 == 0) ? bufA[d4 / 4] : bc4[d4];
                    a0 = fmaf(ar[4*d4+0], f.x, a0);
                    a1 = fmaf(ar[4*d4+1], f.y, a1);
                    a2 = fmaf(ar[4*d4+2], f.z, a2);
                    a3 = fmaf(ar[4*d4+3], f.w, a3);
                }
                float dot = (a0 + a1) + (a2 + a3);
                float key = fmaf(-2.0f, dot, sqb[jA]);   // byte-identical key
                unsigned ub = __float_as_uint(key);
                ub ^= (0x80000000u | (unsigned)((int)ub >> 31));
                vA = ((unsigned long long)ub << 32) | (unsigned)jA;
            }
        }
        // row B exact key
        {
            float ar[DD];
            const float4* a4 = reinterpret_cast<const float4*>(xnT + (size_t)tB * DD);
#pragma unroll
            for (int d = 0; d < DD; d += 4) {
                float4 f = a4[d >> 2];
                ar[d] = f.x; ar[d+1] = f.y; ar[d+2] = f.z; ar[d+3] = f.w;
            }
            if (hvB) {
                const float4* bc4 = reinterpret_cast<const float4*>(Bb + (size_t)jB * DD);
                float a0 = 0, a1 = 0, a2 = 0, a3 = 0;
#pragma unroll
                for (int d4 = 0; d4 < 16; ++d4) {
                    float4 f = (d4 % 4 == 0) ? bufB[d4 / 4] : bc4[d4];
                    a0 = fmaf(ar[4*d4+0], f.x, a0);
                    a1 = fmaf(ar[4*d4+1], f.y, a1);
                    a2 = fmaf(ar[4*d4+2], f.z, a2);
                    a3 = fmaf(ar[4*d4+3], f.w, a3);
                }
                float dot = (a0 + a1) + (a2 + a3);
                float key = fmaf(-2.0f, dot, sqb[jB]);
                unsigned ub = __float_as_uint(key);
                ub ^= (0x80000000u | (unsigned)((int)ub >> 31));
                vB = ((unsigned long long)ub << 32) | (unsigned)jB;
            }
        }
    }
#pragma unroll
    for (int k = 2; k <= 64; k <<= 1) {
#pragma unroll
        for (int jj = k >> 1; jj >= 1; jj >>= 1) {
            unsigned long long oA = __shfl_xor(vA, jj);
            unsigned long long oB = __shfl_xor(vB, jj);
            bool keepMin = (((lane & jj) == 0) == ((lane & k) == 0));
            {
                bool less = oA < vA;
                unsigned long long mn = less ? oA : vA;
                unsigned long long mx = less ? vA : oA;
                vA = keepMin ? mn : mx;
            }
            {
                bool less = oB < vB;
                unsigned long long mn = less ? oB : vB;
                unsigned long long mx = less ? vB : oB;
                vB = keepMin ? mn : mx;
            }
        }
    }
    unsigned long long koutA = vA, koutB = vB;

    // rare fallback: S1 > 64 -> exact per-lane kd[9] + 9-round butterfly
    auto exact_kd = [&](int tX, int totalX, bool ovfX,
                        const unsigned short* glX) -> unsigned long long {
        float ar[DD];
        const float4* a4 = reinterpret_cast<const float4*>(xnT + (size_t)tX * DD);
#pragma unroll
        for (int d = 0; d < DD; d += 4) {
            float4 f = a4[d >> 2];
            ar[d] = f.x; ar[d+1] = f.y; ar[d+2] = f.z; ar[d+3] = f.w;
        }
        unsigned long long kd[KK];
#pragma unroll
        for (int m = 0; m < KK; ++m) kd[m] = ~0ULL;
        const int nI = (totalX + 63) >> 6;
#pragma unroll 1
        for (int m = 0; m < nI; ++m) {
            const int idx = m * 64 + lane;
            if (idx >= totalX) continue;
            int j = ovfX ? idx : s_to_j((int)glX[idx >> 4], idx & 15);
            const float4* bc4 = reinterpret_cast<const float4*>(Bb + (size_t)j * DD);
            float a0 = 0, a1 = 0, a2 = 0, a3 = 0;
#pragma unroll
            for (int d4 = 0; d4 < 16; ++d4) {
                float4 f = bc4[d4];
                a0 = fmaf(ar[4*d4+0], f.x, a0);
                a1 = fmaf(ar[4*d4+1], f.y, a1);
                a2 = fmaf(ar[4*d4+2], f.z, a2);
                a3 = fmaf(ar[4*d4+3], f.w, a3);
            }
            float dot = (a0 + a1) + (a2 + a3);
            float key = fmaf(-2.0f, dot, sqb[j]);
            unsigned ub = __float_as_uint(key);
            ub ^= (0x80000000u | (unsigned)((int)ub >> 31));
            unsigned long long cnd = ((unsigned long long)ub << 32) | (unsigned)j;
            if (cnd < kd[KK - 1]) {
#pragma unroll
                for (int m2 = 0; m2 < KK; ++m2) {
                    bool sw = cnd < kd[m2];
                    unsigned long long lo = sw ? cnd : kd[m2];
                    unsigned long long hi = sw ? kd[m2] : cnd;
                    kd[m2] = lo;
                    cnd = hi;
                }
            }
        }
        unsigned long long ko = ~0ULL;
#pragma unroll
        for (int r = 0; r < KK; ++r) {
            unsigned long long c = kd[0];
            unsigned long long wm = c;
#pragma unroll
            for (int d = 1; d < 64; d <<= 1) {
                unsigned long long o = __shfl_xor(wm, d);
                wm = (o < wm) ? o : wm;
            }
            if (lane == r) ko = wm;
            if (c == wm) {
#pragma unroll
                for (int m2 = 0; m2 < KK - 1; ++m2) kd[m2] = kd[m2 + 1];
                kd[KK - 1] = ~0ULL;
            }
        }
        return ko;
    };
    if (S1A > 64) koutA = exact_kd(tA, totalA, ovfA, glA);
    if (S1B > 64) koutB = exact_kd(tB, totalB, ovfB, glB);

    if (lane < KK) {
        out[(size_t)tA * KK + lane] = (int)(koutA & 0xFFFFFFFFULL);
        out[(size_t)BB * NN * KK + (size_t)tA * KK + lane] = nA;
        out[(size_t)tB * KK + lane] = (int)(koutB & 0xFFFFFFFFULL);
        out[(size_t)BB * NN * KK + (size_t)tB * KK + lane] = nB;
    }
}

// ===========================================================================
// OLD PATH (verified fallback) -- unchanged
// ===========================================================================
__global__ __launch_bounds__(256) void knorm_kernel(const float* __restrict__ x,
                                                    float* __restrict__ xnT,
                                                    float* __restrict__ sq) {
    int t = blockIdx.x * 256 + threadIdx.x;
    int b = t >> 13;
    int n = t & (NN - 1);
    const float* xb = x + (size_t)b * DD * NN + n;
    float v[DD];
    float ss = 0.0f;
#pragma unroll
    for (int d = 0; d < DD; ++d) {
        v[d] = xb[(size_t)d * NN];
        ss = fmaf(v[d], v[d], ss);
    }
    float norm = sqrtf(ss);
    float inv = 1.0f / fmaxf(norm, 1e-12f);
    float s2 = 0.0f;
#pragma unroll
    for (int d = 0; d < DD; ++d) {
        float xv = v[d] * inv;
        v[d] = xv;
        s2 = fmaf(xv, xv, s2);
    }
    float4* o4 = reinterpret_cast<float4*>(xnT + (size_t)t * DD);
#pragma unroll
    for (int d = 0; d < DD; d += 4) {
        o4[d >> 2] = make_float4(v[d], v[d + 1], v[d + 2], v[d + 3]);
    }
    sq[t] = s2;
}

template <int S>
__global__ __launch_bounds__(256, 2) void kdist_kernel(const float* __restrict__ xnT,
                                                       const float* __restrict__ sq,
                                                       unsigned long long* __restrict__ cand) {
    const int rb = blockIdx.x;
    const int b = rb >> 5;
    const int nbase = (rb & 31) * 256;
    const int n = nbase + threadIdx.x;
    const int s = blockIdx.y;
    const int jcount = NN / S;
    const int j0 = s * jcount;
    const int j1 = j0 + jcount;

    const float* __restrict__ Bb = xnT + ((size_t)b * NN) * DD;
    const float* __restrict__ sqb = sq + (size_t)b * NN;

    float ar[DD];
    {
        const float4* a4 = reinterpret_cast<const float4*>(Bb + (size_t)n * DD);
#pragma unroll
        for (int d = 0; d < DD; d += 4) {
            float4 f = a4[d >> 2];
            ar[d] = f.x; ar[d + 1] = f.y; ar[d + 2] = f.z; ar[d + 3] = f.w;
        }
    }
#pragma unroll
    for (int d = 0; d < DD; ++d) {
        asm volatile("" : "+v"(ar[d]));
    }

    unsigned long long kd[KK];
#pragma unroll
    for (int m = 0; m < KK; ++m) kd[m] = ~0ULL;

#pragma unroll 2
    for (int j = j0; j < j1; ++j) {
        const float4* bc4 = reinterpret_cast<const float4*>(Bb + (size_t)j * DD);
        float a0 = 0.0f, a1 = 0.0f, a2 = 0.0f, a3 = 0.0f;
#pragma unroll
        for (int d4 = 0; d4 < DD / 4; ++d4) {
            float4 f = bc4[d4];
            a0 = fmaf(ar[4 * d4 + 0], f.x, a0);
            a1 = fmaf(ar[4 * d4 + 1], f.y, a1);
            a2 = fmaf(ar[4 * d4 + 2], f.z, a2);
            a3 = fmaf(ar[4 * d4 + 3], f.w, a3);
        }
        float dot = (a0 + a1) + (a2 + a3);
        float key = fmaf(-2.0f, dot, sqb[j]);
        unsigned int ub = __float_as_uint(key);
        ub ^= (0x80000000u | (unsigned int)((int)ub >> 31));
        unsigned long long cnd = ((unsigned long long)ub << 32) | (unsigned int)j;
        if (cnd < kd[KK - 1]) {
#pragma unroll
            for (int m = 0; m < KK; ++m) {
                bool sw = cnd < kd[m];
                unsigned long long lo = sw ? cnd : kd[m];
                unsigned long long hi = sw ? kd[m] : cnd;
                kd[m] = lo;
                cnd = hi;
            }
        }
    }

    unsigned long long* outc = cand + ((size_t)(b * NN + n) * S + s) * KK;
#pragma unroll
    for (int m = 0; m < KK; ++m) outc[m] = kd[m];
}

template <int S>
__global__ __launch_bounds__(256) void kmerge_kernel(const unsigned long long* __restrict__ cand,
                                                     int* __restrict__ out) {
    int t = blockIdx.x * 256 + threadIdx.x;
    const unsigned long long* c = cand + (size_t)t * (S * KK);
    unsigned long long kd[KK];
#pragma unroll
    for (int m = 0; m < KK; ++m) kd[m] = ~0ULL;
#pragma unroll
    for (int q = 0; q < S * KK; ++q) {
        unsigned long long cnd = c[q];
        if (cnd < kd[KK - 1]) {
#pragma unroll
            for (int m = 0; m < KK; ++m) {
                bool sw = cnd < kd[m];
                unsigned long long lo = sw ? cnd : kd[m];
                unsigned long long hi = sw ? kd[m] : cnd;
                kd[m] = lo;
                cnd = hi;
            }
        }
    }
    int n = t & (NN - 1);
    int* out0 = out + (size_t)t * KK;
    int* out1 = out + (size_t)BB * NN * KK + (size_t)t * KK;
#pragma unroll
    for (int m = 0; m < KK; ++m) {
        out0[m] = (int)(kd[m] & 0xFFFFFFFFULL);
        out1[m] = n;
    }
}

extern "C" void kernel_launch(void* const* d_in, const int* in_sizes, int n_in,
                              void* d_out, int out_size, void* d_ws, size_t ws_size,
                              hipStream_t stream) {
    const float* x = (const float*)d_in[0];
    int* out = (int*)d_out;
    char* ws = (char*)d_ws;

    // Shared layout head
    constexpr size_t XNT_B = (size_t)BB * NN * DD * 4;          //  8,388,608
    constexpr size_t SQ_B  = (size_t)BB * NN * 4;               //    131,072
    float* xnT = (float*)ws;
    float* sq  = (float*)(ws + XNT_B);

    // New-path layout (offsets kept from the verified R2 layout; Plo/Slo slots
    // unused but reserved so NEED_NEW is unchanged; minbuf fp16 = 32MB of the
    // 64MB reserved region)
    constexpr size_t BF_B  = (size_t)BB * NN * DD * 2;          //  4,194,304 each
    constexpr size_t OFF_PHI = XNT_B + SQ_B;
    constexpr size_t OFF_PLO = OFF_PHI + BF_B;
    constexpr size_t OFF_SHI = OFF_PLO + BF_B;
    constexpr size_t OFF_SLO = OFF_SHI + BF_B;
    constexpr size_t OFF_MIN = OFF_SLO + BF_B;
    constexpr size_t MIN_B   = (size_t)512 * BB * NN * 4;       // 67,108,864 (reserved)
    constexpr size_t NEED_NEW = OFF_MIN + MIN_B;                // 92,405,760

    if (ws_size >= NEED_NEW) {
        unsigned short* Phi = (unsigned short*)(ws + OFF_PHI);
        unsigned short* Shi = (unsigned short*)(ws + OFF_SHI);
        unsigned short* minbuf16 = (unsigned short*)(ws + OFF_MIN);

        knorm2_kernel<<<dim3(BB * NN / 256), dim3(256), 0, stream>>>(x, xnT, sq, Phi, Shi);
        kmin_kernel<<<dim3(BB * NN / 256, 8), dim3(256), 0, stream>>>(Shi, Phi, minbuf16);
        ksel_kernel<<<dim3(BB * NN / 8), dim3(256), 0, stream>>>(xnT, sq, minbuf16, Phi, out);
        return;
    }

    // Old verified path
    unsigned long long* cand = (unsigned long long*)(ws + XNT_B + SQ_B);
    const size_t base = XNT_B + SQ_B;
    const size_t need8 = base + (size_t)BB * NN * 8 * KK * 8;

    knorm_kernel<<<dim3(BB * NN / 256), dim3(256), 0, stream>>>(x, xnT, sq);
    if (ws_size >= need8) {
        kdist_kernel<8><<<dim3(BB * NN / 256, 8), dim3(256), 0, stream>>>(xnT, sq, cand);
        kmerge_kernel<8><<<dim3(BB * NN / 256), dim3(256), 0, stream>>>(cand, out);
    } else {
        kdist_kernel<4><<<dim3(BB * NN / 256, 4), dim3(256), 0, stream>>>(xnT, sq, cand);
        kmerge_kernel<4><<<dim3(BB * NN / 256), dim3(256), 0, stream>>>(cand, out);
    }
}

// Round 13
// 213.693 us; speedup vs baseline: 1.7960x; 1.1382x over previous
//
#include <hip/hip_runtime.h>

// Problem constants (fixed by setup_inputs): x (4, 64, 8192, 1) fp32, k=9, dilation=1
#define BB 4
#define DD 64
#define NN 8192
#define KK 9

// ---------------------------------------------------------------------------
// MFMA filter + exact rescan
//   K1 knorm2: normalize, emit fp32 xnT, sq, fp16 casts P=fp16(xn), S=fp16(-2xn)
//   K2 kmin:   fp16 MFMA GEMM -> per-(row, 16-j-group) min of approx -2*dot.
//              R12 restructure (kmin model-vs-measured gap ~15x with all pipes
//              idle per R2 PMC => exposed A-gather latency + 4x redundant
//              traffic): the block's 4 waves scan IDENTICAL j-tiles, so the
//              A-tile (32 j x 64 k fp16 = 4KB) is now cooperatively reg-staged
//              into double-buffered XOR-swizzled LDS (elem ^= (row&7)<<3 on
//              BOTH write and read sides), one barrier per tile; waves read
//              fragments via ds_read_b128. Next tile's global loads issue at
//              iter top (latency hides under consume). 16 jsplits.
//              minbuf16 layout: s = jsplit*32 + half*16 + u; one full 64B
//              line per row per block flush (fp16, R10 numerics: RNE once).
//   K3 ksel:   UNCHANGED from R11 except s_to_j for the new layout (pure
//              group relabel; theta/kappa proofs are order-stat invariant).
//              (R8-R11: ksel converged at ~118us across 4 orthogonal nulls.)
//   [R13 note: R12 never ran — container infra failure; resubmitted identical
//    after re-audit: dbuf hazards (1 barrier/tile covers both directions),
//    swizzle involution identical on write/read sides, s_to_j inversion
//    matches the HW-verified 32x32 C-row formula.]
// Fallback to the original verified path if ws_size is too small.
// ---------------------------------------------------------------------------

typedef __attribute__((ext_vector_type(8))) _Float16 f16x8;  // 4 VGPR MFMA operand
typedef __attribute__((ext_vector_type(16))) float f32x16;   // 32x32 accumulator
typedef __attribute__((ext_vector_type(2))) _Float16 h2;     // v_dot2 operand
struct H2x4 { h2 a, b, c, d; };

__device__ __forceinline__ uint4 pack8(const unsigned* w) {
    return make_uint4(w[0] | (w[1] << 16), w[2] | (w[3] << 16),
                      w[4] | (w[5] << 16), w[6] | (w[7] << 16));
}

__device__ __forceinline__ float min3f(float a, float b, float c) {
    return fminf(fminf(a, b), c);            // clang fuses to v_min3_f32
}

__device__ __forceinline__ float dot2acc(h2 g, h2 r, float acc) {
#if __has_builtin(__builtin_amdgcn_fdot2)
    return __builtin_amdgcn_fdot2(g, r, acc, false);
#else
    acc = fmaf((float)g[0], (float)r[0], acc);
    return fmaf((float)g[1], (float)r[1], acc);
#endif
}

// storage-index -> j mapping: s = jsplit*32 + half*16 + u (16 jsplits, u in [0,16))
// tile T = jsplit*16 + u ; j = T*32 + (s4>>2)*8 + half*4 + (s4&3)
__device__ __forceinline__ int s_to_j(int g, int s4) {
    int T = ((g >> 5) << 4) + (g & 15);
    return (T << 5) + ((s4 >> 2) << 3) + (((g >> 4) & 1) << 2) + (s4 & 3);
}

// ---------------- K1: normalize + fp32 pack + sq + fp16 casts -----------------
__global__ __launch_bounds__(256) void knorm2_kernel(const float* __restrict__ x,
                                                     float* __restrict__ xnT,
                                                     float* __restrict__ sq,
                                                     unsigned short* __restrict__ Phi,
                                                     unsigned short* __restrict__ Shi) {
    int t = blockIdx.x * 256 + threadIdx.x;      // row id 0..B*N-1
    int b = t >> 13;
    int n = t & (NN - 1);
    const float* xb = x + (size_t)b * DD * NN + n;
    float v[DD];
    float ss = 0.0f;
#pragma unroll
    for (int d = 0; d < DD; ++d) {
        v[d] = xb[(size_t)d * NN];
        ss = fmaf(v[d], v[d], ss);
    }
    float inv = 1.0f / fmaxf(sqrtf(ss), 1e-12f);
    float s2 = 0.0f;
#pragma unroll
    for (int d = 0; d < DD; ++d) {
        v[d] *= inv;
        s2 = fmaf(v[d], v[d], s2);
    }
    sq[t] = s2;
    float4* o4 = reinterpret_cast<float4*>(xnT + (size_t)t * DD);
#pragma unroll
    for (int d = 0; d < DD; d += 4) o4[d >> 2] = make_float4(v[d], v[d+1], v[d+2], v[d+3]);

    size_t base = (size_t)t * DD;
#pragma unroll
    for (int d0 = 0; d0 < DD; d0 += 8) {
        unsigned ph[8], sh[8];
#pragma unroll
        for (int e = 0; e < 8; ++e) {
            float f = v[d0 + e];
            _Float16 hp = (_Float16)f;               // v_cvt_f16_f32 (RNE)
            _Float16 hs = (_Float16)(-2.0f * f);     // exact scale before rounding
            ph[e] = (unsigned)__builtin_bit_cast(unsigned short, hp);
            sh[e] = (unsigned)__builtin_bit_cast(unsigned short, hs);
        }
        *reinterpret_cast<uint4*>(Phi + base + d0) = pack8(ph);
        *reinterpret_cast<uint4*>(Shi + base + d0) = pack8(sh);
    }
}

// ---------------- K2: MFMA min pass (LDS-staged A, fp16 stage/minbuf) --------
// Block = 4 waves x 64 i-rows = 256 rows; grid (128 rowblocks, 16 jsplits);
// 16 tiles/block, all 4 waves consume the SAME staged A-tile per step.
__global__ __launch_bounds__(256, 4) void kmin_kernel(const unsigned short* __restrict__ Shi,
                                                      const unsigned short* __restrict__ Phi,
                                                      unsigned short* __restrict__ minbuf16) {
    __shared__ unsigned short Ast[2][2048];              // 2 x 4KB A-tile (swizzled)
    __shared__ unsigned short stage[4][64][34];          // 17.4KB fp16 min-stage
    const int tid = threadIdx.x;
    const int lane = tid & 63;
    const int wave = tid >> 6;
    const int l31 = lane & 31;
    const int half = lane >> 5;
    const int i0 = blockIdx.x * 256 + wave * 64;         // global i-row base
    const int b = blockIdx.x >> 5;                       // batch (32 rowblocks each)
    const int jloc0 = blockIdx.y * 512;                  // batch-local j start
    const size_t jrow0 = (size_t)b * NN + jloc0;         // first global j-row

    // B fragments (two 32-row sets; 8 MFMA per staged tile)
    f16x8 Bh0[4], Bh1[4];
    {
        const size_t ib0 = (size_t)(i0 + l31) * DD + half * 8;
        const size_t ib1 = (size_t)(i0 + 32 + l31) * DD + half * 8;
#pragma unroll
        for (int kc = 0; kc < 4; ++kc) {
            Bh0[kc] = *reinterpret_cast<const f16x8*>(Phi + ib0 + kc * 16);
            Bh1[kc] = *reinterpret_cast<const f16x8*>(Phi + ib1 + kc * 16);
        }
    }

    // staging piece for this thread: row (of 32), 16B piece p (of 8)
    const int srow = tid >> 3;
    const int sp = tid & 7;
    const unsigned soff = (unsigned)(srow * 64 + ((sp * 8) ^ ((srow & 7) << 3)));
    const size_t gbase = (jrow0 + srow) * DD + sp * 8;

    // prologue: stage tile 0
    {
        uint4 g = *reinterpret_cast<const uint4*>(Shi + gbase);
        *reinterpret_cast<uint4*>(&Ast[0][soff]) = g;
    }
    __syncthreads();

    int cur = 0;
#pragma unroll 1
    for (int t = 0; t < 16; ++t) {
        // issue next tile's global loads early (latency hides under consume)
        uint4 gnext;
        const bool hasNext = (t + 1) < 16;
        if (hasNext)
            gnext = *reinterpret_cast<const uint4*>(Shi + gbase + (size_t)(t + 1) * 32 * DD);

        // consume staged tile: 4 swizzled ds_read_b128 + 8 MFMA + min trees
        f16x8 Ah[4];
#pragma unroll
        for (int kc = 0; kc < 4; ++kc) {
            unsigned off = (unsigned)(l31 * 64 + ((half * 8 + kc * 16) ^ ((l31 & 7) << 3)));
            Ah[kc] = *reinterpret_cast<const f16x8*>(&Ast[cur][off]);
        }
        f32x16 c0 = {}, c1 = {};
#pragma unroll
        for (int kc = 0; kc < 4; ++kc)
            c0 = __builtin_amdgcn_mfma_f32_32x32x16_f16(Ah[kc], Bh0[kc], c0, 0, 0, 0);
#pragma unroll
        for (int kc = 0; kc < 4; ++kc)
            c1 = __builtin_amdgcn_mfma_f32_32x32x16_f16(Ah[kc], Bh1[kc], c1, 0, 0, 0);
        const int col = half * 16 + t;
        {
            float q0 = min3f(c0[0], c0[1], c0[2]);
            float q1 = min3f(c0[3], c0[4], c0[5]);
            float q2 = min3f(c0[6], c0[7], c0[8]);
            float q3 = min3f(c0[9], c0[10], c0[11]);
            float q4 = min3f(c0[12], c0[13], c0[14]);
            float mv = fminf(min3f(q0, q1, q2), min3f(q3, q4, c0[15]));
            stage[wave][l31][col] = (unsigned short)__builtin_bit_cast(unsigned short, (_Float16)mv);
        }
        {
            float q0 = min3f(c1[0], c1[1], c1[2]);
            float q1 = min3f(c1[3], c1[4], c1[5]);
            float q2 = min3f(c1[6], c1[7], c1[8]);
            float q3 = min3f(c1[9], c1[10], c1[11]);
            float q4 = min3f(c1[12], c1[13], c1[14]);
            float mv = fminf(min3f(q0, q1, q2), min3f(q3, q4, c1[15]));
            stage[wave][32 + l31][col] = (unsigned short)__builtin_bit_cast(unsigned short, (_Float16)mv);
        }

        // write next tile into the other buffer, then one barrier per tile.
        // Hazards: (w1) write(nxt,t) vs read(nxt,t+1) -> this barrier;
        //          (w2) write(nxt,t) vs read(nxt as cur, t-1) -> previous barrier.
        if (hasNext)
            *reinterpret_cast<uint4*>(&Ast[cur ^ 1][soff]) = gnext;
        __syncthreads();
        cur ^= 1;
    }

    // flush: one full 64B line per row: minbuf16[row*512 + blockIdx.y*32 .. +32]
    unsigned short* dst0 = minbuf16 + (size_t)blockIdx.y * 32;
#pragma unroll
    for (int it = 0; it < 4; ++it) {
        int idx = it * 64 + lane;                        // 0..255
        int r = idx >> 2;                                // 0..63
        int p = idx & 3;                                 // 16B piece (8 fp16)
        const unsigned* s32 = reinterpret_cast<const unsigned*>(&stage[wave][r][p * 8]);
        uint4 vv = make_uint4(s32[0], s32[1], s32[2], s32[3]);
        *reinterpret_cast<uint4*>(dst0 + (size_t)(i0 + r) * 512 + p * 8) = vv;
    }
}

// ---------------- K3: 2 rows per wave, interleaved chains (R11) --------------
__global__ __launch_bounds__(256) void ksel_kernel(const float* __restrict__ xnT,
                                                   const float* __restrict__ sq,
                                                   const unsigned short* __restrict__ minbuf16,
                                                   const unsigned short* __restrict__ Phi,
                                                   int* __restrict__ out) {
    __shared__ unsigned short glist[4][2][40];           // wave-private
    __shared__ unsigned short jlist[4][2][64];           // wave-private
    const int lane = threadIdx.x & 63;
    const int wave = threadIdx.x >> 6;
    const int tA = __builtin_amdgcn_readfirstlane(blockIdx.x * 8 + wave * 2);
    const int tB = tA + 1;
    const int b = tA >> 13;                              // pair shares batch (8|8192)
    const int nA = tA & (NN - 1);
    const int nB = tB & (NN - 1);

    float gmA[8], gmB[8];
    {
        uint4 a = *reinterpret_cast<const uint4*>(minbuf16 + (size_t)tA * 512 + lane * 8);
        uint4 c = *reinterpret_cast<const uint4*>(minbuf16 + (size_t)tB * 512 + lane * 8);
        unsigned wa[4] = {a.x, a.y, a.z, a.w};
        unsigned wb[4] = {c.x, c.y, c.z, c.w};
#pragma unroll
        for (int q4 = 0; q4 < 4; ++q4) {
            gmA[q4*2+0] = (float)__builtin_bit_cast(_Float16, (unsigned short)(wa[q4] & 0xFFFFu));
            gmA[q4*2+1] = (float)__builtin_bit_cast(_Float16, (unsigned short)(wa[q4] >> 16));
            gmB[q4*2+0] = (float)__builtin_bit_cast(_Float16, (unsigned short)(wb[q4] & 0xFFFFu));
            gmB[q4*2+1] = (float)__builtin_bit_cast(_Float16, (unsigned short)(wb[q4] >> 16));
        }
    }

    float svA = fminf(min3f(gmA[0], gmA[1], gmA[2]),
                      fminf(min3f(gmA[3], gmA[4], gmA[5]), fminf(gmA[6], gmA[7])));
    float svB = fminf(min3f(gmB[0], gmB[1], gmB[2]),
                      fminf(min3f(gmB[3], gmB[4], gmB[5]), fminf(gmB[6], gmB[7])));
#pragma unroll
    for (int k = 2; k <= 64; k <<= 1) {
#pragma unroll
        for (int jj = k >> 1; jj >= 1; jj >>= 1) {
            float oA = __shfl_xor(svA, jj);
            float oB = __shfl_xor(svB, jj);
            bool keepMin = (((lane & jj) == 0) == ((lane & k) == 0));
            svA = keepMin ? fminf(svA, oA) : fmaxf(svA, oA);
            svB = keepMin ? fminf(svB, oB) : fmaxf(svB, oB);
        }
    }
    const float th9pA = __shfl(svA, 8);
    const float th9pB = __shfl(svB, 8);
    const float thetaA  = th9pA + 8e-3f,  thetaB  = th9pB + 8e-3f;
    const float kappa1A = th9pA + 7.5e-3f, kappa1B = th9pB + 7.5e-3f;

    int cntA = 0, cntB = 0;
    unsigned short* glA = &glist[wave][0][0];
    unsigned short* glB = &glist[wave][1][0];
#pragma unroll
    for (int q = 0; q < 8; ++q) {
        bool cA = gmA[q] <= thetaA;
        unsigned long long mA = __ballot(cA);
        int pA = cntA + __popcll(mA & ((1ULL << lane) - 1ULL));
        if (cA && pA < 40) glA[pA] = (unsigned short)(lane * 8 + q);
        cntA += (int)__popcll(mA);
        bool cB = gmB[q] <= thetaB;
        unsigned long long mB = __ballot(cB);
        int pB = cntB + __popcll(mB & ((1ULL << lane) - 1ULL));
        if (cB && pB < 40) glB[pB] = (unsigned short)(lane * 8 + q);
        cntB += (int)__popcll(mB);
    }
    // no __syncthreads: lists are wave-private; within-wave LDS ordering is
    // program-order (block barrier would only couple the 4 waves).

    const unsigned short* __restrict__ Pb = Phi + ((size_t)b * NN) * DD;
    H2x4 arhA[8], arhB[8];
    {
        const f16x8* prA = reinterpret_cast<const f16x8*>(Phi + (size_t)tA * DD);
        const f16x8* prB = reinterpret_cast<const f16x8*>(Phi + (size_t)tB * DD);
#pragma unroll
        for (int c8 = 0; c8 < 8; ++c8) {
            arhA[c8] = __builtin_bit_cast(H2x4, prA[c8]);
            arhB[c8] = __builtin_bit_cast(H2x4, prB[c8]);
        }
    }

    const bool ovfA = (cntA > 40), ovfB = (cntB > 40);
    const int totalA = ovfA ? NN : cntA * 16;
    const int totalB = ovfB ? NN : cntB * 16;
    const int nItA = (totalA + 63) >> 6, nItB = (totalB + 63) >> 6;
    const int nIt = nItA > nItB ? nItA : nItB;
    int S1A = 0, S1B = 0;
    unsigned short* jlA = &jlist[wave][0][0];
    unsigned short* jlB = &jlist[wave][1][0];
#pragma unroll 1
    for (int m = 0; m < nIt; ++m) {
        const int idx = m * 64 + lane;
        const bool actA = idx < totalA;
        const bool actB = idx < totalB;
        float m2A = __uint_as_float(0x7f800000u);
        float m2B = __uint_as_float(0x7f800000u);
        int jA = 0, jB = 0;
        if (actA) {
            jA = ovfA ? idx : s_to_j((int)glA[idx >> 4], idx & 15);
            const f16x8* p8 = reinterpret_cast<const f16x8*>(Pb + (size_t)jA * DD);
            float a0 = 0.0f, a1 = 0.0f, a2 = 0.0f, a3 = 0.0f;
#pragma unroll
            for (int c8 = 0; c8 < 8; ++c8) {
                H2x4 g2 = __builtin_bit_cast(H2x4, p8[c8]);
                a0 = dot2acc(g2.a, arhA[c8].a, a0);
                a1 = dot2acc(g2.b, arhA[c8].b, a1);
                a2 = dot2acc(g2.c, arhA[c8].c, a2);
                a3 = dot2acc(g2.d, arhA[c8].d, a3);
            }
            m2A = -2.0f * ((a0 + a1) + (a2 + a3));
        }
        if (actB) {
            jB = ovfB ? idx : s_to_j((int)glB[idx >> 4], idx & 15);
            const f16x8* p8 = reinterpret_cast<const f16x8*>(Pb + (size_t)jB * DD);
            float a0 = 0.0f, a1 = 0.0f, a2 = 0.0f, a3 = 0.0f;
#pragma unroll
            for (int c8 = 0; c8 < 8; ++c8) {
                H2x4 g2 = __builtin_bit_cast(H2x4, p8[c8]);
                a0 = dot2acc(g2.a, arhB[c8].a, a0);
                a1 = dot2acc(g2.b, arhB[c8].b, a1);
                a2 = dot2acc(g2.c, arhB[c8].c, a2);
                a3 = dot2acc(g2.d, arhB[c8].d, a3);
            }
            m2B = -2.0f * ((a0 + a1) + (a2 + a3));
        }
        bool passA = actA && (m2A <= kappa1A);
        unsigned long long mA = __ballot(passA);
        int pA = S1A + __popcll(mA & ((1ULL << lane) - 1ULL));
        if (passA && pA < 64) jlA[pA] = (unsigned short)jA;
        S1A += (int)__popcll(mA);
        bool passB = actB && (m2B <= kappa1B);
        unsigned long long mB = __ballot(passB);
        int pB = S1B + __popcll(mB & ((1ULL << lane) - 1ULL));
        if (passB && pB < 64) jlB[pB] = (unsigned short)jB;
        S1B += (int)__popcll(mB);
    }

    const float* __restrict__ Bb = xnT + (size_t)b * NN * DD;
    const float* __restrict__ sqb = sq + (size_t)b * NN;

    unsigned long long vA = ~0ULL, vB = ~0ULL;
    {
        float4 bufA[4], bufB[4];
        int jA = 0, jB = 0;
        const bool hvA = lane < (S1A <= 64 ? S1A : 64);
        const bool hvB = lane < (S1B <= 64 ? S1B : 64);
        if (hvA) {
            jA = (int)jlA[lane];
            const float4* bc4 = reinterpret_cast<const float4*>(Bb + (size_t)jA * DD);
#pragma unroll
            for (int p = 0; p < 4; ++p) bufA[p] = bc4[p * 4];     // [0,4,8,12]
        }
        if (hvB) {
            jB = (int)jlB[lane];
            const float4* bc4 = reinterpret_cast<const float4*>(Bb + (size_t)jB * DD);
#pragma unroll
            for (int p = 0; p < 4; ++p) bufB[p] = bc4[p * 4];
        }
        {
            float ar[DD];
            const float4* a4 = reinterpret_cast<const float4*>(xnT + (size_t)tA * DD);
#pragma unroll
            for (int d = 0; d < DD; d += 4) {
                float4 f = a4[d >> 2];
                ar[d] = f.x; ar[d+1] = f.y; ar[d+2] = f.z; ar[d+3] = f.w;
            }
            if (hvA) {
                const float4* bc4 = reinterpret_cast<const float4*>(Bb + (size_t)jA * DD);
                float a0 = 0, a1 = 0, a2 = 0, a3 = 0;
#pragma unroll
                for (int d4 = 0; d4 < 16; ++d4) {
                    float4 f = (d4 % 4 == 0) ? bufA[d4 / 4] : bc4[d4];
                    a0 = fmaf(ar[4*d4+0], f.x, a0);
                    a1 = fmaf(ar[4*d4+1], f.y, a1);
                    a2 = fmaf(ar[4*d4+2], f.z, a2);
                    a3 = fmaf(ar[4*d4+3], f.w, a3);
                }
                float dot = (a0 + a1) + (a2 + a3);
                float key = fmaf(-2.0f, dot, sqb[jA]);   // byte-identical key
                unsigned ub = __float_as_uint(key);
                ub ^= (0x80000000u | (unsigned)((int)ub >> 31));
                vA = ((unsigned long long)ub << 32) | (unsigned)jA;
            }
        }
        {
            float ar[DD];
            const float4* a4 = reinterpret_cast<const float4*>(xnT + (size_t)tB * DD);
#pragma unroll
            for (int d = 0; d < DD; d += 4) {
                float4 f = a4[d >> 2];
                ar[d] = f.x; ar[d+1] = f.y; ar[d+2] = f.z; ar[d+3] = f.w;
            }
            if (hvB) {
                const float4* bc4 = reinterpret_cast<const float4*>(Bb + (size_t)jB * DD);
                float a0 = 0, a1 = 0, a2 = 0, a3 = 0;
#pragma unroll
                for (int d4 = 0; d4 < 16; ++d4) {
                    float4 f = (d4 % 4 == 0) ? bufB[d4 / 4] : bc4[d4];
                    a0 = fmaf(ar[4*d4+0], f.x, a0);
                    a1 = fmaf(ar[4*d4+1], f.y, a1);
                    a2 = fmaf(ar[4*d4+2], f.z, a2);
                    a3 = fmaf(ar[4*d4+3], f.w, a3);
                }
                float dot = (a0 + a1) + (a2 + a3);
                float key = fmaf(-2.0f, dot, sqb[jB]);
                unsigned ub = __float_as_uint(key);
                ub ^= (0x80000000u | (unsigned)((int)ub >> 31));
                vB = ((unsigned long long)ub << 32) | (unsigned)jB;
            }
        }
    }
#pragma unroll
    for (int k = 2; k <= 64; k <<= 1) {
#pragma unroll
        for (int jj = k >> 1; jj >= 1; jj >>= 1) {
            unsigned long long oA = __shfl_xor(vA, jj);
            unsigned long long oB = __shfl_xor(vB, jj);
            bool keepMin = (((lane & jj) == 0) == ((lane & k) == 0));
            {
                bool less = oA < vA;
                unsigned long long mn = less ? oA : vA;
                unsigned long long mx = less ? vA : oA;
                vA = keepMin ? mn : mx;
            }
            {
                bool less = oB < vB;
                unsigned long long mn = less ? oB : vB;
                unsigned long long mx = less ? vB : oB;
                vB = keepMin ? mn : mx;
            }
        }
    }
    unsigned long long koutA = vA, koutB = vB;

    auto exact_kd = [&](int tX, int totalX, bool ovfX,
                        const unsigned short* glX) -> unsigned long long {
        float ar[DD];
        const float4* a4 = reinterpret_cast<const float4*>(xnT + (size_t)tX * DD);
#pragma unroll
        for (int d = 0; d < DD; d += 4) {
            float4 f = a4[d >> 2];
            ar[d] = f.x; ar[d+1] = f.y; ar[d+2] = f.z; ar[d+3] = f.w;
        }
        unsigned long long kd[KK];
#pragma unroll
        for (int m = 0; m < KK; ++m) kd[m] = ~0ULL;
        const int nI = (totalX + 63) >> 6;
#pragma unroll 1
        for (int m = 0; m < nI; ++m) {
            const int idx = m * 64 + lane;
            if (idx >= totalX) continue;
            int j = ovfX ? idx : s_to_j((int)glX[idx >> 4], idx & 15);
            const float4* bc4 = reinterpret_cast<const float4*>(Bb + (size_t)j * DD);
            float a0 = 0, a1 = 0, a2 = 0, a3 = 0;
#pragma unroll
            for (int d4 = 0; d4 < 16; ++d4) {
                float4 f = bc4[d4];
                a0 = fmaf(ar[4*d4+0], f.x, a0);
                a1 = fmaf(ar[4*d4+1], f.y, a1);
                a2 = fmaf(ar[4*d4+2], f.z, a2);
                a3 = fmaf(ar[4*d4+3], f.w, a3);
            }
            float dot = (a0 + a1) + (a2 + a3);
            float key = fmaf(-2.0f, dot, sqb[j]);
            unsigned ub = __float_as_uint(key);
            ub ^= (0x80000000u | (unsigned)((int)ub >> 31));
            unsigned long long cnd = ((unsigned long long)ub << 32) | (unsigned)j;
            if (cnd < kd[KK - 1]) {
#pragma unroll
                for (int m2 = 0; m2 < KK; ++m2) {
                    bool sw = cnd < kd[m2];
                    unsigned long long lo = sw ? cnd : kd[m2];
                    unsigned long long hi = sw ? kd[m2] : cnd;
                    kd[m2] = lo;
                    cnd = hi;
                }
            }
        }
        unsigned long long ko = ~0ULL;
#pragma unroll
        for (int r = 0; r < KK; ++r) {
            unsigned long long c = kd[0];
            unsigned long long wm = c;
#pragma unroll
            for (int d = 1; d < 64; d <<= 1) {
                unsigned long long o = __shfl_xor(wm, d);
                wm = (o < wm) ? o : wm;
            }
            if (lane == r) ko = wm;
            if (c == wm) {
#pragma unroll
                for (int m2 = 0; m2 < KK - 1; ++m2) kd[m2] = kd[m2 + 1];
                kd[KK - 1] = ~0ULL;
            }
        }
        return ko;
    };
    if (S1A > 64) koutA = exact_kd(tA, totalA, ovfA, glA);
    if (S1B > 64) koutB = exact_kd(tB, totalB, ovfB, glB);

    if (lane < KK) {
        out[(size_t)tA * KK + lane] = (int)(koutA & 0xFFFFFFFFULL);
        out[(size_t)BB * NN * KK + (size_t)tA * KK + lane] = nA;
        out[(size_t)tB * KK + lane] = (int)(koutB & 0xFFFFFFFFULL);
        out[(size_t)BB * NN * KK + (size_t)tB * KK + lane] = nB;
    }
}

// ===========================================================================
// OLD PATH (verified fallback) -- unchanged
// ===========================================================================
__global__ __launch_bounds__(256) void knorm_kernel(const float* __restrict__ x,
                                                    float* __restrict__ xnT,
                                                    float* __restrict__ sq) {
    int t = blockIdx.x * 256 + threadIdx.x;
    int b = t >> 13;
    int n = t & (NN - 1);
    const float* xb = x + (size_t)b * DD * NN + n;
    float v[DD];
    float ss = 0.0f;
#pragma unroll
    for (int d = 0; d < DD; ++d) {
        v[d] = xb[(size_t)d * NN];
        ss = fmaf(v[d], v[d], ss);
    }
    float norm = sqrtf(ss);
    float inv = 1.0f / fmaxf(norm, 1e-12f);
    float s2 = 0.0f;
#pragma unroll
    for (int d = 0; d < DD; ++d) {
        float xv = v[d] * inv;
        v[d] = xv;
        s2 = fmaf(xv, xv, s2);
    }
    float4* o4 = reinterpret_cast<float4*>(xnT + (size_t)t * DD);
#pragma unroll
    for (int d = 0; d < DD; d += 4) {
        o4[d >> 2] = make_float4(v[d], v[d + 1], v[d + 2], v[d + 3]);
    }
    sq[t] = s2;
}

template <int S>
__global__ __launch_bounds__(256, 2) void kdist_kernel(const float* __restrict__ xnT,
                                                       const float* __restrict__ sq,
                                                       unsigned long long* __restrict__ cand) {
    const int rb = blockIdx.x;
    const int b = rb >> 5;
    const int nbase = (rb & 31) * 256;
    const int n = nbase + threadIdx.x;
    const int s = blockIdx.y;
    const int jcount = NN / S;
    const int j0 = s * jcount;
    const int j1 = j0 + jcount;

    const float* __restrict__ Bb = xnT + ((size_t)b * NN) * DD;
    const float* __restrict__ sqb = sq + (size_t)b * NN;

    float ar[DD];
    {
        const float4* a4 = reinterpret_cast<const float4*>(Bb + (size_t)n * DD);
#pragma unroll
        for (int d = 0; d < DD; d += 4) {
            float4 f = a4[d >> 2];
            ar[d] = f.x; ar[d + 1] = f.y; ar[d + 2] = f.z; ar[d + 3] = f.w;
        }
    }
#pragma unroll
    for (int d = 0; d < DD; ++d) {
        asm volatile("" : "+v"(ar[d]));
    }

    unsigned long long kd[KK];
#pragma unroll
    for (int m = 0; m < KK; ++m) kd[m] = ~0ULL;

#pragma unroll 2
    for (int j = j0; j < j1; ++j) {
        const float4* bc4 = reinterpret_cast<const float4*>(Bb + (size_t)j * DD);
        float a0 = 0.0f, a1 = 0.0f, a2 = 0.0f, a3 = 0.0f;
#pragma unroll
        for (int d4 = 0; d4 < DD / 4; ++d4) {
            float4 f = bc4[d4];
            a0 = fmaf(ar[4 * d4 + 0], f.x, a0);
            a1 = fmaf(ar[4 * d4 + 1], f.y, a1);
            a2 = fmaf(ar[4 * d4 + 2], f.z, a2);
            a3 = fmaf(ar[4 * d4 + 3], f.w, a3);
        }
        float dot = (a0 + a1) + (a2 + a3);
        float key = fmaf(-2.0f, dot, sqb[j]);
        unsigned int ub = __float_as_uint(key);
        ub ^= (0x80000000u | (unsigned int)((int)ub >> 31));
        unsigned long long cnd = ((unsigned long long)ub << 32) | (unsigned int)j;
        if (cnd < kd[KK - 1]) {
#pragma unroll
            for (int m = 0; m < KK; ++m) {
                bool sw = cnd < kd[m];
                unsigned long long lo = sw ? cnd : kd[m];
                unsigned long long hi = sw ? kd[m] : cnd;
                kd[m] = lo;
                cnd = hi;
            }
        }
    }

    unsigned long long* outc = cand + ((size_t)(b * NN + n) * S + s) * KK;
#pragma unroll
    for (int m = 0; m < KK; ++m) outc[m] = kd[m];
}

template <int S>
__global__ __launch_bounds__(256) void kmerge_kernel(const unsigned long long* __restrict__ cand,
                                                     int* __restrict__ out) {
    int t = blockIdx.x * 256 + threadIdx.x;
    const unsigned long long* c = cand + (size_t)t * (S * KK);
    unsigned long long kd[KK];
#pragma unroll
    for (int m = 0; m < KK; ++m) kd[m] = ~0ULL;
#pragma unroll
    for (int q = 0; q < S * KK; ++q) {
        unsigned long long cnd = c[q];
        if (cnd < kd[KK - 1]) {
#pragma unroll
            for (int m = 0; m < KK; ++m) {
                bool sw = cnd < kd[m];
                unsigned long long lo = sw ? cnd : kd[m];
                unsigned long long hi = sw ? kd[m] : cnd;
                kd[m] = lo;
                cnd = hi;
            }
        }
    }
    int n = t & (NN - 1);
    int* out0 = out + (size_t)t * KK;
    int* out1 = out + (size_t)BB * NN * KK + (size_t)t * KK;
#pragma unroll
    for (int m = 0; m < KK; ++m) {
        out0[m] = (int)(kd[m] & 0xFFFFFFFFULL);
        out1[m] = n;
    }
}

extern "C" void kernel_launch(void* const* d_in, const int* in_sizes, int n_in,
                              void* d_out, int out_size, void* d_ws, size_t ws_size,
                              hipStream_t stream) {
    const float* x = (const float*)d_in[0];
    int* out = (int*)d_out;
    char* ws = (char*)d_ws;

    // Shared layout head
    constexpr size_t XNT_B = (size_t)BB * NN * DD * 4;          //  8,388,608
    constexpr size_t SQ_B  = (size_t)BB * NN * 4;               //    131,072
    float* xnT = (float*)ws;
    float* sq  = (float*)(ws + XNT_B);

    // New-path layout (offsets kept from the verified R2 layout; Plo/Slo slots
    // unused but reserved so NEED_NEW is unchanged; minbuf fp16 = 32MB of the
    // 64MB reserved region)
    constexpr size_t BF_B  = (size_t)BB * NN * DD * 2;          //  4,194,304 each
    constexpr size_t OFF_PHI = XNT_B + SQ_B;
    constexpr size_t OFF_PLO = OFF_PHI + BF_B;
    constexpr size_t OFF_SHI = OFF_PLO + BF_B;
    constexpr size_t OFF_SLO = OFF_SHI + BF_B;
    constexpr size_t OFF_MIN = OFF_SLO + BF_B;
    constexpr size_t MIN_B   = (size_t)512 * BB * NN * 4;       // 67,108,864 (reserved)
    constexpr size_t NEED_NEW = OFF_MIN + MIN_B;                // 92,405,760

    if (ws_size >= NEED_NEW) {
        unsigned short* Phi = (unsigned short*)(ws + OFF_PHI);
        unsigned short* Shi = (unsigned short*)(ws + OFF_SHI);
        unsigned short* minbuf16 = (unsigned short*)(ws + OFF_MIN);

        knorm2_kernel<<<dim3(BB * NN / 256), dim3(256), 0, stream>>>(x, xnT, sq, Phi, Shi);
        kmin_kernel<<<dim3(BB * NN / 256, 16), dim3(256), 0, stream>>>(Shi, Phi, minbuf16);
        ksel_kernel<<<dim3(BB * NN / 8), dim3(256), 0, stream>>>(xnT, sq, minbuf16, Phi, out);
        return;
    }

    // Old verified path
    unsigned long long* cand = (unsigned long long*)(ws + XNT_B + SQ_B);
    const size_t base = XNT_B + SQ_B;
    const size_t need8 = base + (size_t)BB * NN * 8 * KK * 8;

    knorm_kernel<<<dim3(BB * NN / 256), dim3(256), 0, stream>>>(x, xnT, sq);
    if (ws_size >= need8) {
        kdist_kernel<8><<<dim3(BB * NN / 256, 8), dim3(256), 0, stream>>>(xnT, sq, cand);
        kmerge_kernel<8><<<dim3(BB * NN / 256), dim3(256), 0, stream>>>(cand, out);
    } else {
        kdist_kernel<4><<<dim3(BB * NN / 256, 4), dim3(256), 0, stream>>>(xnT, sq, cand);
        kmerge_kernel<4><<<dim3(BB * NN / 256), dim3(256), 0, stream>>>(cand, out);
    }
}